// Round 8
// baseline (278.358 us; speedup 1.0000x reference)
//
#include <hip/hip_runtime.h>
#include <hip/hip_bf16.h>
#include <stdint.h>
#include <math.h>

#define HIDDEN 768
#define BATCH 4
#define SEQ 8192
#define NQ 1024
#define PHS_KS 4

typedef __bf16 bf16;
typedef __bf16 bf16x4 __attribute__((ext_vector_type(4)));
typedef __bf16 bf16x8 __attribute__((ext_vector_type(8)));
typedef float f32x4 __attribute__((ext_vector_type(4)));

// General bijective XCD-chunked block-id swizzle (m204 formula).
__device__ inline int xcd_swz() {
  const unsigned n = gridDim.x, o = blockIdx.x;
  const unsigned q = n >> 3, r = n & 7;
  const unsigned x = o & 7, k = o >> 3;
  return (int)((x < r ? x * (q + 1) : r * (q + 1) + (x - r) * q) + k);
}

#define GLOAD16(gptr, lptr)                                                   \
  __builtin_amdgcn_global_load_lds(                                           \
      (const __attribute__((address_space(1))) void*)(gptr),                  \
      (__attribute__((address_space(3))) void*)(lptr), 16, 0, 0)

#define FENCE asm volatile("" ::: "memory")

// ---------------------------------------------------------------------------
__global__ __launch_bounds__(256) void k_cvt(const float* __restrict__ in,
                                             bf16* __restrict__ out, int n4) {
  int stride = gridDim.x * blockDim.x;
  for (int i = blockIdx.x * blockDim.x + threadIdx.x; i < n4; i += stride) {
    float4 v = reinterpret_cast<const float4*>(in)[i];
    bf16x4 o = {(bf16)v.x, (bf16)v.y, (bf16)v.z, (bf16)v.w};
    reinterpret_cast<bf16x4*>(out)[i] = o;
  }
}

// [R][C] fp32 -> [C][R] bf16 tiled transpose-convert (weights).
__global__ __launch_bounds__(256) void k_transpose_w(
    const float* __restrict__ in, bf16* __restrict__ out, int R, int C) {
  __shared__ float tile[32][33];
  const int c0 = blockIdx.x * 32, r0 = blockIdx.y * 32;
  const int tx = threadIdx.x & 31, ty = threadIdx.x >> 5;
#pragma unroll
  for (int i = 0; i < 32; i += 8)
    tile[ty + i][tx] = in[(long)(r0 + ty + i) * C + (c0 + tx)];
  __syncthreads();
#pragma unroll
  for (int i = 0; i < 32; i += 8)
    out[(long)(c0 + ty + i) * R + (r0 + tx)] = (bf16)tile[tx][ty + i];
}

// Fused: hs fp32 [B*S][H] -> hsb bf16 (same layout) + hsT bf16 [B][H][S].
__global__ __launch_bounds__(256) void k_cvt_hs_dual(const float* __restrict__ hs,
                                                     bf16* __restrict__ hsb,
                                                     bf16* __restrict__ hsT) {
  __shared__ float T[32][65];
  const int h0 = blockIdx.x * 64;
  const int s0g = blockIdx.y * 32;
  const int b = s0g >> 13;
  const int sIn = s0g & 8191;
  const int t = threadIdx.x;
  const int r = t >> 3, c = (t & 7) * 8;

  const float* src = hs + (long)(s0g + r) * HIDDEN + h0 + c;
  float4 v0 = *reinterpret_cast<const float4*>(src);
  float4 v1 = *reinterpret_cast<const float4*>(src + 4);
  T[r][c + 0] = v0.x; T[r][c + 1] = v0.y; T[r][c + 2] = v0.z; T[r][c + 3] = v0.w;
  T[r][c + 4] = v1.x; T[r][c + 5] = v1.y; T[r][c + 6] = v1.z; T[r][c + 7] = v1.w;

  bf16x8 o = {(bf16)v0.x, (bf16)v0.y, (bf16)v0.z, (bf16)v0.w,
              (bf16)v1.x, (bf16)v1.y, (bf16)v1.z, (bf16)v1.w};
  *reinterpret_cast<bf16x8*>(hsb + (long)(s0g + r) * HIDDEN + h0 + c) = o;

  __syncthreads();
  const int hh = t >> 2, ss = (t & 3) * 8;
  bf16x8 o2;
#pragma unroll
  for (int k = 0; k < 8; ++k) o2[k] = (bf16)T[ss + k][hh];
  *reinterpret_cast<bf16x8*>(hsT + ((long)b * HIDDEN + h0 + hh) * SEQ + sIn + ss) = o2;
}

// bqk[h] = sum_d bq[d] * Wk[h][d]
__global__ __launch_bounds__(64) void k_gemv_bqk(const float* __restrict__ Wk,
                                                 const float* __restrict__ bq,
                                                 float* __restrict__ bqk) {
  const int h = blockIdx.x, l = threadIdx.x;
  float s = 0.0f;
#pragma unroll
  for (int d = l; d < HIDDEN; d += 64) s += bq[d] * Wk[(long)h * HIDDEN + d];
#pragma unroll
  for (int o = 32; o > 0; o >>= 1) s += __shfl_xor(s, o);
  if (l == 0) bqk[h] = s;
}

// ---------------------------------------------------------------------------
// Small-GEMM workhorse (round-7 verified): 128x128, BK=32, counted-vmcnt.
template <typename OUT>
__global__ __launch_bounds__(256) void k_gemm_bt(
    const bf16* __restrict__ A, const bf16* __restrict__ B, OUT* __restrict__ C,
    const float* __restrict__ bias, int N, int K, float scale,
    int nx, int ny, long strA, long strB, long strC) {
  const int id = xcd_swz();
  const int col = id % nx;
  const int row = (id / nx) % ny;
  const int z = id / (nx * ny);

  __shared__ bf16 smem[16384];

  const int tid = threadIdx.x;
  const int lane = tid & 63, wave = tid >> 6;
  const int wr = wave >> 1, wc = wave & 1;
  const int lr = lane & 15, lk = (lane >> 4) * 8, lg = (lane >> 4) * 4;

  const bf16* At = A + (long)z * strA + (long)row * 128 * K;
  const bf16* Bt = B + (long)z * strB + (long)col * 128 * K;

#define STAGE_TILE(buf, k0)                                                   \
  {                                                                           \
    bf16* dA = smem + (buf) * 4096;                                           \
    bf16* dB = smem + 8192 + (buf) * 4096;                                    \
    _Pragma("unroll") for (int h = 0; h < 2; ++h) {                           \
      const int cch = tid + h * 256;                                          \
      const int rr = cch >> 2, cc = (cch & 3) * 8;                            \
      GLOAD16(At + (long)rr * K + (k0) + cc, (char*)dA + cch * 16);           \
      GLOAD16(Bt + (long)rr * K + (k0) + cc, (char*)dB + cch * 16);           \
    }                                                                         \
  }

  STAGE_TILE(0, 0);

  f32x4 acc[4][4] = {};
  const int nt = K / 32;
  int cur = 0;
#pragma unroll 1
  for (int t = 0; t < nt; ++t) {
    FENCE;
    __builtin_amdgcn_s_barrier();
    FENCE;
    if (t + 1 < nt) {
      STAGE_TILE(cur ^ 1, (t + 1) * 32);
      asm volatile("s_waitcnt vmcnt(4)" ::: "memory");
    } else {
      asm volatile("s_waitcnt vmcnt(0)" ::: "memory");
    }
    __builtin_amdgcn_s_barrier();
    FENCE;
    const bf16* rA = smem + cur * 4096;
    const bf16* rB = smem + 8192 + cur * 4096;
    bf16x8 af[4], bfr[4];
#pragma unroll
    for (int m = 0; m < 4; ++m)
      af[m] = *reinterpret_cast<const bf16x8*>(&rA[(wr * 64 + m * 16 + lr) * 32 + lk]);
#pragma unroll
    for (int n = 0; n < 4; ++n)
      bfr[n] = *reinterpret_cast<const bf16x8*>(&rB[(wc * 64 + n * 16 + lr) * 32 + lk]);
    __builtin_amdgcn_s_setprio(1);
#pragma unroll
    for (int m = 0; m < 4; ++m)
#pragma unroll
      for (int n = 0; n < 4; ++n)
        acc[m][n] = __builtin_amdgcn_mfma_f32_16x16x32_bf16(af[m], bfr[n], acc[m][n], 0, 0, 0);
    __builtin_amdgcn_s_setprio(0);
    cur ^= 1;
  }
#undef STAGE_TILE

  if constexpr (__is_same(OUT, float)) {
    float* Cb = (float*)C + (long)z * strC;
#pragma unroll
    for (int m = 0; m < 4; ++m)
#pragma unroll
      for (int n = 0; n < 4; ++n) {
        const int gc = col * 128 + wc * 64 + n * 16 + lr;
        const float bv = bias ? bias[gc] : 0.0f;
#pragma unroll
        for (int j = 0; j < 4; ++j) {
          const int gr = row * 128 + wr * 64 + m * 16 + lg + j;
          Cb[(long)gr * N + gc] = acc[m][n][j] * scale + bv;
        }
      }
  } else {
    FENCE;
    __builtin_amdgcn_s_barrier();
    FENCE;
#pragma unroll
    for (int m = 0; m < 4; ++m)
#pragma unroll
      for (int n = 0; n < 4; ++n) {
        const int gc = col * 128 + wc * 64 + n * 16 + lr;
        const float bv = bias ? bias[gc] : 0.0f;
#pragma unroll
        for (int j = 0; j < 4; ++j)
          smem[(wr * 64 + m * 16 + lg + j) * 128 + wc * 64 + n * 16 + lr] =
              (bf16)(acc[m][n][j] * scale + bv);
      }
    __syncthreads();
    OUT* Cb = C + (long)z * strC;
    const long rb = (long)row * 128, cb = (long)col * 128;
#pragma unroll
    for (int i = 0; i < 8; ++i) {
      const int ch = tid + i * 256;
      const int rr = ch >> 4;
      const int ce = (ch & 15) * 8;
      *reinterpret_cast<bf16x8*>(&Cb[(rb + rr) * N + cb + ce]) =
          *reinterpret_cast<const bf16x8*>(smem + ch * 8);
    }
  }
}

// ---------------------------------------------------------------------------
// 8-phase-style pipelined 256x256 GEMM (m201 port, derived geometry):
// BK=64 (2 k-halves), 8 waves (2M x 4N), per-wave 128x64 out, acc[8][4].
// LDS 128 KB: A [dbuf2][half2][128][64] @0, B same @64K. C bounced via LDS.
// 4 phases/K-tile: {ds_read frags | stage half-tiles of t+1 | barrier |
//   setprio1 16xMFMA setprio0 | barrier}; vmcnt(0) once per K-tile AFTER
//   p3's MFMA (loads get >=2.5 phases of flight).
// Swizzle (derived, hand-traced): physical colchunk = logical ^ ((row>>2)&3),
// inverse applied on the gload source; read slot = l16 ^ (lr>>2).
// MODE 1: scores  C = exp((A.B^T)*scale + maskbias) + rowsum partials.
// MODE 2: PHS     C[kc] = P-chunk . hsT^T (bf16 partial), K-chunk 2048.
template <int MODE>
__global__ __launch_bounds__(512, 2) void k_gemm256(
    const bf16* __restrict__ A, const bf16* __restrict__ B, bf16* __restrict__ C,
    const float* __restrict__ mask, float* __restrict__ rspart,
    float scale, int NT) {
  __shared__ bf16 smem[65536];  // 128 KB
  char* smc = (char*)smem;
  const int tid = threadIdx.x;
  const int lane = tid & 63;
  const int wave = tid >> 6;
  const int wm = wave >> 2;   // 0..1  M-half
  const int wn = wave & 3;    // 0..3  64-col slice
  const int lr = lane & 15;
  const int l16 = lane >> 4;
  const int slot = ((l16 ^ (lr >> 2)) & 3) * 16;
  const int aoff = lr * 128 + slot;
  const int boff = (wn & 1) * 8192 + lr * 128 + slot;

  int row, col, z, kc = 0;
  long ldA, ldB;
  const bf16 *Ap, *Bp;
  if constexpr (MODE == 1) {
    const int id = blockIdx.x;                 // 4 x 32 x 4 = 512
    row = id & 3; col = (id >> 2) & 31; z = id >> 7;
    Ap = A + ((long)z * NQ + row * 256) * HIDDEN;  ldA = HIDDEN;
    Bp = B + ((long)z * SEQ + col * 256) * HIDDEN; ldB = HIDDEN;
  } else {
    const int id = blockIdx.x;                 // 3 x 4 x 4 x 4 = 192
    col = id % 3; int r = id / 3; row = r & 3; r >>= 2; z = r & 3; kc = r >> 2;
    Ap = A + ((long)z * NQ + row * 256) * SEQ + kc * (SEQ / PHS_KS);  ldA = SEQ;
    Bp = B + ((long)z * HIDDEN + col * 256) * SEQ + kc * (SEQ / PHS_KS); ldB = SEQ;
  }

  // stage one 128x64 half-tile (1024 chunks of 16B, 2/thread), swizzled source
  auto STG = [&](const bf16* gbase, long ld, int k0, char* dst) {
#pragma unroll
    for (int h = 0; h < 2; ++h) {
      const int c = tid + h * 512;
      const int r = c >> 3;
      const int q = (c & 7) ^ ((r >> 2) & 3);
      GLOAD16(gbase + (long)r * ld + k0 + q * 8, dst + c * 16);
    }
  };

  f32x4 acc[8][4] = {};

  // prologue: tile 0, all 4 half-tiles
  STG(Ap, ldA, 0, smc);
  STG(Bp, ldB, 0, smc + 65536);
  STG(Ap + 128 * ldA, ldA, 0, smc + 16384);
  STG(Bp + 128 * ldB, ldB, 0, smc + 65536 + 16384);
  asm volatile("s_waitcnt vmcnt(0)" ::: "memory");
  __builtin_amdgcn_s_barrier();
  FENCE;

#pragma unroll 1
  for (int t = 0; t < NT; ++t) {
    const int d = t & 1;
    const char* sA = smc + d * 32768 + wm * 16384;
    const char* sB = smc + 65536 + d * 32768 + (wn >> 1) * 16384;
    char* nA = smc + (d ^ 1) * 32768;
    char* nB = smc + 65536 + (d ^ 1) * 32768;
    const int nk0 = (t + 1) * 64;
    bf16x8 af[4], bfv[4];

    // -------- phase 0: (mh0, ks0) + stage A0,B0 of t+1 --------
#pragma unroll
    for (int n = 0; n < 4; ++n)
      bfv[n] = *reinterpret_cast<const bf16x8*>(sB + boff + n * 2048);
#pragma unroll
    for (int mm = 0; mm < 4; ++mm)
      af[mm] = *reinterpret_cast<const bf16x8*>(sA + aoff + mm * 2048);
    if (t + 1 < NT) { STG(Ap, ldA, nk0, nA); STG(Bp, ldB, nk0, nB); }
    FENCE; __builtin_amdgcn_s_barrier(); FENCE;
    __builtin_amdgcn_s_setprio(1);
#pragma unroll
    for (int mm = 0; mm < 4; ++mm)
#pragma unroll
      for (int n = 0; n < 4; ++n)
        acc[mm][n] = __builtin_amdgcn_mfma_f32_16x16x32_bf16(af[mm], bfv[n], acc[mm][n], 0, 0, 0);
    __builtin_amdgcn_s_setprio(0);
    FENCE; __builtin_amdgcn_s_barrier(); FENCE;

    // -------- phase 1: (mh1, ks0) + stage A1,B1 of t+1 --------
#pragma unroll
    for (int mm = 0; mm < 4; ++mm)
      af[mm] = *reinterpret_cast<const bf16x8*>(sA + 8192 + aoff + mm * 2048);
    if (t + 1 < NT) {
      STG(Ap + 128 * ldA, ldA, nk0, nA + 16384);
      STG(Bp + 128 * ldB, ldB, nk0, nB + 16384);
    }
    FENCE; __builtin_amdgcn_s_barrier(); FENCE;
    __builtin_amdgcn_s_setprio(1);
#pragma unroll
    for (int mm = 0; mm < 4; ++mm)
#pragma unroll
      for (int n = 0; n < 4; ++n)
        acc[4 + mm][n] = __builtin_amdgcn_mfma_f32_16x16x32_bf16(af[mm], bfv[n], acc[4 + mm][n], 0, 0, 0);
    __builtin_amdgcn_s_setprio(0);
    FENCE; __builtin_amdgcn_s_barrier(); FENCE;

    // -------- phase 2: (mh0, ks1) --------
#pragma unroll
    for (int n = 0; n < 4; ++n)
      bfv[n] = *reinterpret_cast<const bf16x8*>(sB + boff + n * 2048 + 64);
#pragma unroll
    for (int mm = 0; mm < 4; ++mm)
      af[mm] = *reinterpret_cast<const bf16x8*>(sA + aoff + mm * 2048 + 64);
    FENCE; __builtin_amdgcn_s_barrier(); FENCE;
    __builtin_amdgcn_s_setprio(1);
#pragma unroll
    for (int mm = 0; mm < 4; ++mm)
#pragma unroll
      for (int n = 0; n < 4; ++n)
        acc[mm][n] = __builtin_amdgcn_mfma_f32_16x16x32_bf16(af[mm], bfv[n], acc[mm][n], 0, 0, 0);
    __builtin_amdgcn_s_setprio(0);
    FENCE; __builtin_amdgcn_s_barrier(); FENCE;

    // -------- phase 3: (mh1, ks1) + vmcnt drain (loads had ~3 phases) ------
#pragma unroll
    for (int mm = 0; mm < 4; ++mm)
      af[mm] = *reinterpret_cast<const bf16x8*>(sA + 8192 + aoff + mm * 2048 + 64);
    FENCE; __builtin_amdgcn_s_barrier(); FENCE;
    __builtin_amdgcn_s_setprio(1);
#pragma unroll
    for (int mm = 0; mm < 4; ++mm)
#pragma unroll
      for (int n = 0; n < 4; ++n)
        acc[4 + mm][n] = __builtin_amdgcn_mfma_f32_16x16x32_bf16(af[mm], bfv[n], acc[4 + mm][n], 0, 0, 0);
    __builtin_amdgcn_s_setprio(0);
    asm volatile("s_waitcnt vmcnt(0)" ::: "memory");
    FENCE; __builtin_amdgcn_s_barrier(); FENCE;
  }

  // -------- epilogue: scatter to LDS [256][256], then coalesced copy-out ---
  float rsv[8][4];
  if constexpr (MODE == 1) {
#pragma unroll
    for (int m = 0; m < 8; ++m)
#pragma unroll
      for (int j = 0; j < 4; ++j) rsv[m][j] = 0.0f;
  }
#pragma unroll
  for (int m = 0; m < 8; ++m) {
#pragma unroll
    for (int n = 0; n < 4; ++n) {
      const int lc = wn * 64 + n * 16 + lr;
      float mbv = 0.0f;
      if constexpr (MODE == 1)
        mbv = (1.0f - mask[(long)z * SEQ + col * 256 + lc]) * -10000.0f;
#pragma unroll
      for (int j = 0; j < 4; ++j) {
        float v = acc[m][n][j];
        if constexpr (MODE == 1) {
          v = expf(v * scale + mbv);
          rsv[m][j] += v;
        }
        smem[(wm * 128 + m * 16 + l16 * 4 + j) * 256 + lc] = (bf16)v;
      }
    }
  }
  if constexpr (MODE == 1) {
#pragma unroll
    for (int m = 0; m < 8; ++m)
#pragma unroll
      for (int j = 0; j < 4; ++j) {
        float v = rsv[m][j];
        v += __shfl_xor(v, 1); v += __shfl_xor(v, 2);
        v += __shfl_xor(v, 4); v += __shfl_xor(v, 8);
        if (lr == 0)
          rspart[((long)z * NQ + row * 256 + wm * 128 + m * 16 + l16 * 4 + j) * 128 +
                 col * 4 + wn] = v;
      }
  }
  __syncthreads();

  bf16* Cb;
  long ldc;
  if constexpr (MODE == 1) {
    Cb = C + ((long)z * NQ + row * 256) * SEQ + (long)col * 256;
    ldc = SEQ;
  } else {
    Cb = C + ((long)(kc * BATCH + z) * NQ + row * 256) * HIDDEN + (long)col * 256;
    ldc = HIDDEN;
  }
#pragma unroll
  for (int i = 0; i < 16; ++i) {
    const int ch = tid + i * 512;   // 8192 chunks of 16B = 256x256 bf16
    const int rr = ch >> 5;
    const int ce = (ch & 31) * 8;
    *reinterpret_cast<bf16x8*>(&Cb[(long)rr * ldc + ce]) =
        *reinterpret_cast<const bf16x8*>((const char*)smem + ch * 16);
  }
}

// rowsum[row] = sum of 128 partial slots
__global__ __launch_bounds__(256) void k_rowsum(const float* __restrict__ rp,
                                                float* __restrict__ rs) {
  const int t = threadIdx.x;
  const int row = blockIdx.x * 8 + (t >> 5);
  const int s = t & 31;
  const float* base = rp + (long)row * 128;
  float v = base[s] + base[s + 32] + base[s + 64] + base[s + 96];
  v += __shfl_xor(v, 1); v += __shfl_xor(v, 2); v += __shfl_xor(v, 4);
  v += __shfl_xor(v, 8); v += __shfl_xor(v, 16);
  if (s == 0) rs[row] = v;
}

// ctx1 = (sum of PHS_KS bf16 partials) / rowsum[row]
__global__ __launch_bounds__(256) void k_reduceN(const bf16* __restrict__ p,
                                                 const float* __restrict__ rs,
                                                 bf16* __restrict__ out, int n8) {
  const long NB = (long)BATCH * NQ * HIDDEN;
  const int stride = gridDim.x * blockDim.x;
  for (int i = blockIdx.x * blockDim.x + threadIdx.x; i < n8; i += stride) {
    float acc[8] = {};
#pragma unroll
    for (int k = 0; k < PHS_KS; ++k) {
      bf16x8 v = reinterpret_cast<const bf16x8*>(p + k * NB)[i];
#pragma unroll
      for (int j = 0; j < 8; ++j) acc[j] += (float)v[j];
    }
    const float inv = 1.0f / rs[i / 96];
    bf16x8 o;
#pragma unroll
    for (int j = 0; j < 8; ++j) o[j] = (bf16)(acc[j] * inv);
    reinterpret_cast<bf16x8*>(out)[i] = o;
  }
}

// ---------------------------------------------------------------------------
extern "C" void kernel_launch(void* const* d_in, const int* in_sizes, int n_in,
                              void* d_out, int out_size, void* d_ws, size_t ws_size,
                              hipStream_t stream) {
  const float* hs = (const float*)d_in[0];
  const float* qu = (const float*)d_in[1];
  const float* mask = (const float*)d_in[2];
  const float* Wq = (const float*)d_in[3];
  const float* bq = (const float*)d_in[4];
  const float* Wk = (const float*)d_in[5];
  const float* Wv = (const float*)d_in[7];
  const float* bv = (const float*)d_in[8];
  float* out = (float*)d_out;
  // bk (d_in[6]) adds a softmax-row-constant -> cancels exactly.

  const size_t HS_N = (size_t)BATCH * SEQ * HIDDEN;
  const size_t QU_N = (size_t)BATCH * NQ * HIDDEN;
  const size_t W_N = (size_t)HIDDEN * HIDDEN;
  const size_t P_N = (size_t)BATCH * NQ * SEQ;

  char* ws = (char*)d_ws;
  size_t off = 0;
  auto alloc = [&](size_t bytes) {
    char* p = ws + off;
    off += (bytes + 255) & ~(size_t)255;
    return p;
  };

  // regionA: hsb (live through scores) / PHS partials (after) — overlap
  char* regionA = alloc(HS_N * 2);
  bf16* hsb = (bf16*)regionA;
  bf16* Ppart = (bf16*)regionA;         // PHS_KS(4) * QU_N bf16 = 25 MB
  bf16* hsT = (bf16*)alloc(HS_N * 2);
  bf16* Pr = (bf16*)alloc(P_N * 2);
  bf16* qub = (bf16*)alloc(QU_N * 2);
  bf16* tmpb = (bf16*)alloc(QU_N * 2);
  bf16* ctx1 = (bf16*)alloc(QU_N * 2);
  bf16* Wkb = (bf16*)alloc(W_N * 2);
  bf16* Wqb = (bf16*)alloc(W_N * 2);
  bf16* WvT = (bf16*)alloc(W_N * 2);
  bf16* Mt = (bf16*)alloc(W_N * 2);
  float* bqk = (float*)alloc(HIDDEN * 4);
  float* rspart = (float*)alloc((size_t)BATCH * NQ * 128 * 4);
  float* rowsum = (float*)alloc((size_t)BATCH * NQ * 4);

  // 1) converts + fused hs prep
  k_cvt<<<dim3(1024), dim3(256), 0, stream>>>(qu, qub, (int)(QU_N / 4));
  k_cvt<<<dim3(576), dim3(256), 0, stream>>>(Wk, Wkb, (int)(W_N / 4));
  k_cvt<<<dim3(576), dim3(256), 0, stream>>>(Wq, Wqb, (int)(W_N / 4));
  k_transpose_w<<<dim3(24, 24), dim3(256), 0, stream>>>(Wv, WvT, HIDDEN, HIDDEN);
  k_cvt_hs_dual<<<dim3(12, 1024), dim3(256), 0, stream>>>(hs, hsb, hsT);
  k_gemv_bqk<<<dim3(768), dim3(64), 0, stream>>>(Wk, bq, bqk);

  // 2) Mt = Wk.Wq^T  [768x768]
  k_gemm_bt<bf16><<<dim3(36), dim3(256), 0, stream>>>(
      Wkb, Wqb, Mt, nullptr, HIDDEN, HIDDEN, 1.0f, 6, 6, 0, 0, 0);

  // 3) folded query: tmp = qub.Mt^T + bqk  [4096x768]
  k_gemm_bt<bf16><<<dim3(192), dim3(256), 0, stream>>>(
      qub, Mt, tmpb, bqk, HIDDEN, HIDDEN, 1.0f, 6, 32, 0, 0, 0);

  // 4) scores: Pr = exp(tmp.hsb^T/sqrt(H) + maskbias), rowsum partials
  const float qkscale = 1.0f / sqrtf((float)HIDDEN);
  k_gemm256<1><<<dim3(512), dim3(512), 0, stream>>>(
      tmpb, hsb, Pr, mask, rspart, qkscale, HIDDEN / 64);
  k_rowsum<<<dim3(BATCH * NQ / 8), dim3(256), 0, stream>>>(rspart, rowsum);

  // 5) PHS partials: Ppart[kc] = P[:, kc-chunk] . hsT^T  (overwrites dead hsb)
  k_gemm256<2><<<dim3(192), dim3(512), 0, stream>>>(
      Pr, hsT, Ppart, nullptr, nullptr, 1.0f, (SEQ / PHS_KS) / 64);

  // 6) ctx1 = (sum partials) / rowsum
  k_reduceN<<<dim3(1536), dim3(256), 0, stream>>>(Ppart, rowsum, ctx1, (int)(QU_N / 8));

  // 7) V-fold: out = ctx1.Wv + bv
  k_gemm_bt<float><<<dim3(192), dim3(256), 0, stream>>>(
      ctx1, WvT, out, bv, HIDDEN, HIDDEN, 1.0f, 6, 32, 0, 0, 0);
}

// Round 9
// 257.801 us; speedup vs baseline: 1.0797x; 1.0797x over previous
//
#include <hip/hip_runtime.h>
#include <hip/hip_bf16.h>
#include <stdint.h>
#include <math.h>

#define HIDDEN 768
#define BATCH 4
#define SEQ 8192
#define NQ 1024
#define PHS_KS 4

typedef __bf16 bf16;
typedef __bf16 bf16x4 __attribute__((ext_vector_type(4)));
typedef __bf16 bf16x8 __attribute__((ext_vector_type(8)));
typedef float f32x4 __attribute__((ext_vector_type(4)));

// General bijective XCD-chunked block-id swizzle (m204 formula, any grid size).
__device__ inline int xcd_swz() {
  const unsigned n = gridDim.x, o = blockIdx.x;
  const unsigned q = n >> 3, r = n & 7;
  const unsigned x = o & 7, k = o >> 3;
  return (int)((x < r ? x * (q + 1) : r * (q + 1) + (x - r) * q) + k);
}

#define GLOAD16(gptr, lptr)                                                   \
  __builtin_amdgcn_global_load_lds(                                           \
      (const __attribute__((address_space(1))) void*)(gptr),                  \
      (__attribute__((address_space(3))) void*)(lptr), 16, 0, 0)

#define FENCE asm volatile("" ::: "memory")

// ---------------------------------------------------------------------------
// fp32 -> bf16 elementwise convert (float4 vectorized, grid-stride)
__global__ __launch_bounds__(256) void k_cvt(const float* __restrict__ in,
                                             bf16* __restrict__ out, int n4) {
  int stride = gridDim.x * blockDim.x;
  for (int i = blockIdx.x * blockDim.x + threadIdx.x; i < n4; i += stride) {
    float4 v = reinterpret_cast<const float4*>(in)[i];
    bf16x4 o = {(bf16)v.x, (bf16)v.y, (bf16)v.z, (bf16)v.w};
    reinterpret_cast<bf16x4*>(out)[i] = o;
  }
}

// ---------------------------------------------------------------------------
// [R][C] fp32 -> [C][R] bf16 tiled transpose-convert (weights).
__global__ __launch_bounds__(256) void k_transpose_w(
    const float* __restrict__ in, bf16* __restrict__ out, int R, int C) {
  __shared__ float tile[32][33];
  const int c0 = blockIdx.x * 32, r0 = blockIdx.y * 32;
  const int tx = threadIdx.x & 31, ty = threadIdx.x >> 5;  // 32 x 8
#pragma unroll
  for (int i = 0; i < 32; i += 8)
    tile[ty + i][tx] = in[(long)(r0 + ty + i) * C + (c0 + tx)];
  __syncthreads();
#pragma unroll
  for (int i = 0; i < 32; i += 8)
    out[(long)(c0 + ty + i) * R + (r0 + tx)] = (bf16)tile[tx][ty + i];
}

// ---------------------------------------------------------------------------
// Fused: hs fp32 [B*S][H] -> hsb bf16 (same layout) + hsT bf16 [B][H][S].
__global__ __launch_bounds__(256) void k_cvt_hs_dual(const float* __restrict__ hs,
                                                     bf16* __restrict__ hsb,
                                                     bf16* __restrict__ hsT) {
  __shared__ float T[32][65];
  const int h0 = blockIdx.x * 64;
  const int s0g = blockIdx.y * 32;  // global row in [0, B*S)
  const int b = s0g >> 13;          // / 8192
  const int sIn = s0g & 8191;
  const int t = threadIdx.x;
  const int r = t >> 3, c = (t & 7) * 8;

  const float* src = hs + (long)(s0g + r) * HIDDEN + h0 + c;
  float4 v0 = *reinterpret_cast<const float4*>(src);
  float4 v1 = *reinterpret_cast<const float4*>(src + 4);
  T[r][c + 0] = v0.x; T[r][c + 1] = v0.y; T[r][c + 2] = v0.z; T[r][c + 3] = v0.w;
  T[r][c + 4] = v1.x; T[r][c + 5] = v1.y; T[r][c + 6] = v1.z; T[r][c + 7] = v1.w;

  bf16x8 o = {(bf16)v0.x, (bf16)v0.y, (bf16)v0.z, (bf16)v0.w,
              (bf16)v1.x, (bf16)v1.y, (bf16)v1.z, (bf16)v1.w};
  *reinterpret_cast<bf16x8*>(hsb + (long)(s0g + r) * HIDDEN + h0 + c) = o;

  __syncthreads();
  const int hh = t >> 2, ss = (t & 3) * 8;
  bf16x8 o2;
#pragma unroll
  for (int k = 0; k < 8; ++k) o2[k] = (bf16)T[ss + k][hh];
  *reinterpret_cast<bf16x8*>(hsT + ((long)b * HIDDEN + h0 + hh) * SEQ + sIn + ss) = o2;
}

// bqk[h] = sum_d bq[d] * Wk[h][d]
__global__ __launch_bounds__(64) void k_gemv_bqk(const float* __restrict__ Wk,
                                                 const float* __restrict__ bq,
                                                 float* __restrict__ bqk) {
  const int h = blockIdx.x, l = threadIdx.x;
  float s = 0.0f;
#pragma unroll
  for (int d = l; d < HIDDEN; d += 64) s += bq[d] * Wk[(long)h * HIDDEN + d];
#pragma unroll
  for (int o = 32; o > 0; o >>= 1) s += __shfl_xor(s, o);
  if (l == 0) bqk[h] = s;
}

// ---------------------------------------------------------------------------
// C[M,N] = (A[M,K].B[N,K]^T)*scale + bias[col]      (MODE 0)
//        = exp((A.B^T)*scale + maskbias[z][col])    (MODE 1, bf16 out + rowsums)
// 128x128 tile, BK=32, 4 waves, 16x16x32 MFMA, global_load_lds w16.
// K-loop: TRIPLE-buffered, prefetch distance 2 — per-thread 4 loads/STAGE,
// steady state 12 outstanding, s_waitcnt vmcnt(8) => tile t landed while
// t+1/t+2 stay in flight across the barrier (loads age ~2 compute steps).
// bf16 outputs bounce through LDS for clean coalesced 16B-lane stores.
template <typename OUT, int MODE>
__global__ __launch_bounds__(256) void k_gemm_bt(
    const bf16* __restrict__ A, const bf16* __restrict__ B, OUT* __restrict__ C,
    const float* __restrict__ bias, const float* __restrict__ mask,
    float* __restrict__ rspart, int N, int K, float scale,
    int nx, int ny, int rowfast, long strA, long strB, long strC) {
  const int id = xcd_swz();
  int col, row, z;
  if (rowfast) {
    row = id % ny; col = (id / ny) % nx; z = id / (ny * nx);
  } else {
    col = id % nx; row = (id / nx) % ny; z = id / (nx * ny);
  }

  __shared__ bf16 smem[24576];  // A: 3x4096 @0, B: 3x4096 @12288 (48 KB)

  const int tid = threadIdx.x;
  const int lane = tid & 63, wave = tid >> 6;
  const int wr = wave >> 1, wc = wave & 1;
  const int lr = lane & 15, lk = (lane >> 4) * 8, lg = (lane >> 4) * 4;

  const bf16* At = A + (long)z * strA + (long)row * 128 * K;
  const bf16* Bt = B + (long)z * strB + (long)col * 128 * K;

#define STAGE_TILE(buf, k0)                                                   \
  {                                                                           \
    bf16* dA = smem + (buf) * 4096;                                           \
    bf16* dB = smem + 12288 + (buf) * 4096;                                   \
    _Pragma("unroll") for (int h = 0; h < 2; ++h) {                           \
      const int cch = tid + h * 256;                                          \
      const int rr = cch >> 2, cc = (cch & 3) * 8;                            \
      GLOAD16(At + (long)rr * K + (k0) + cc, (char*)dA + cch * 16);           \
      GLOAD16(Bt + (long)rr * K + (k0) + cc, (char*)dB + cch * 16);           \
    }                                                                         \
  }

  const int nt = K / 32;
  STAGE_TILE(0, 0);
  if (nt > 1) STAGE_TILE(1, 32);

  f32x4 acc[4][4] = {};
#pragma unroll 1
  for (int t = 0; t < nt; ++t) {
    FENCE;
    __builtin_amdgcn_s_barrier();  // B0: reads of tile t-1 done -> buf (t+2)%3 free
    FENCE;
    if (t + 2 < nt) {
      STAGE_TILE((t + 2) % 3, (t + 2) * 32);
      asm volatile("s_waitcnt vmcnt(8)" ::: "memory");  // tile t landed; t+1,t+2 in flight
    } else if (t + 2 == nt) {
      asm volatile("s_waitcnt vmcnt(4)" ::: "memory");
    } else {
      asm volatile("s_waitcnt vmcnt(0)" ::: "memory");
    }
    __builtin_amdgcn_s_barrier();  // B1: tile t resident for every thread
    FENCE;
    const bf16* rA = smem + (t % 3) * 4096;
    const bf16* rB = smem + 12288 + (t % 3) * 4096;
    bf16x8 af[4], bfr[4];
#pragma unroll
    for (int m = 0; m < 4; ++m)
      af[m] = *reinterpret_cast<const bf16x8*>(&rA[(wr * 64 + m * 16 + lr) * 32 + lk]);
#pragma unroll
    for (int n = 0; n < 4; ++n)
      bfr[n] = *reinterpret_cast<const bf16x8*>(&rB[(wc * 64 + n * 16 + lr) * 32 + lk]);
    __builtin_amdgcn_s_setprio(1);
#pragma unroll
    for (int m = 0; m < 4; ++m)
#pragma unroll
      for (int n = 0; n < 4; ++n)
        acc[m][n] = __builtin_amdgcn_mfma_f32_16x16x32_bf16(af[m], bfr[n], acc[m][n], 0, 0, 0);
    __builtin_amdgcn_s_setprio(0);
  }
#undef STAGE_TILE

  if constexpr (__is_same(OUT, float)) {
    float* Cb = (float*)C + (long)z * strC;
#pragma unroll
    for (int m = 0; m < 4; ++m)
#pragma unroll
      for (int n = 0; n < 4; ++n) {
        const int gc = col * 128 + wc * 64 + n * 16 + lr;
        const float bv = bias ? bias[gc] : 0.0f;
#pragma unroll
        for (int j = 0; j < 4; ++j) {
          const int gr = row * 128 + wr * 64 + m * 16 + lg + j;
          Cb[(long)gr * N + gc] = acc[m][n][j] * scale + bv;
        }
      }
  } else {
    FENCE;
    __builtin_amdgcn_s_barrier();  // staging LDS now reused as C tile
    FENCE;
    float rsv[4][4];
    if constexpr (MODE == 1) {
#pragma unroll
      for (int m = 0; m < 4; ++m)
#pragma unroll
        for (int j = 0; j < 4; ++j) rsv[m][j] = 0.0f;
    }
#pragma unroll
    for (int m = 0; m < 4; ++m)
#pragma unroll
      for (int n = 0; n < 4; ++n) {
        const int gc = col * 128 + wc * 64 + n * 16 + lr;
        float bv = 0.0f, mbv = 0.0f;
        if constexpr (MODE == 0) bv = bias ? bias[gc] : 0.0f;
        if constexpr (MODE == 1) mbv = (1.0f - mask[(long)z * SEQ + gc]) * -10000.0f;
#pragma unroll
        for (int j = 0; j < 4; ++j) {
          float v = acc[m][n][j] * scale;
          if constexpr (MODE == 1) {
            v = expf(v + mbv);
            rsv[m][j] += v;
          } else {
            v += bv;
          }
          smem[(wr * 64 + m * 16 + lg + j) * 128 + wc * 64 + n * 16 + lr] = (bf16)v;
        }
      }
    if constexpr (MODE == 1) {
#pragma unroll
      for (int m = 0; m < 4; ++m)
#pragma unroll
        for (int j = 0; j < 4; ++j) {
          float v = rsv[m][j];
          v += __shfl_xor(v, 1); v += __shfl_xor(v, 2);
          v += __shfl_xor(v, 4); v += __shfl_xor(v, 8);
          if ((lane & 15) == 0) {
            const int gr = row * 128 + wr * 64 + m * 16 + lg + j;
            rspart[((long)z * NQ + gr) * 128 + col * 2 + wc] = v;
          }
        }
    }
    __syncthreads();
    OUT* Cb = C + (long)z * strC;
    const long rb = (long)row * 128, cb = (long)col * 128;
#pragma unroll
    for (int i = 0; i < 8; ++i) {
      const int ch = tid + i * 256;     // 2048 chunks of 16B
      const int rr = ch >> 4;
      const int ce = (ch & 15) * 8;
      *reinterpret_cast<bf16x8*>(&Cb[(rb + rr) * N + cb + ce]) =
          *reinterpret_cast<const bf16x8*>(smem + ch * 8);
    }
  }
}

// rowsum[row] = sum of 128 partial slots (deterministic reduce)
__global__ __launch_bounds__(256) void k_rowsum(const float* __restrict__ rp,
                                                float* __restrict__ rs) {
  const int t = threadIdx.x;
  const int row = blockIdx.x * 8 + (t >> 5);
  const int s = t & 31;
  const float* base = rp + (long)row * 128;
  float v = base[s] + base[s + 32] + base[s + 64] + base[s + 96];
  v += __shfl_xor(v, 1); v += __shfl_xor(v, 2); v += __shfl_xor(v, 4);
  v += __shfl_xor(v, 8); v += __shfl_xor(v, 16);
  if (s == 0) rs[row] = v;
}

// ---------------------------------------------------------------------------
// PHS split-K partial GEMM: Cpart[kc][b,q,:] = P[b, q-tile, kc-chunk] . hsT^T
// Triple-buffered depth-2 pipeline, KS=4 (K-chunk 2048, grid 768).
#define PHS_KC (SEQ / PHS_KS)
__global__ __launch_bounds__(256) void k_gemm_phs(const bf16* __restrict__ P,
                                                  const bf16* __restrict__ HT,
                                                  bf16* __restrict__ Cp) {
  const int id = xcd_swz();
  const int col = id % 6;
  int r = id / 6;
  const int row = r % 8;
  r /= 8;
  const int b = r % 4;
  const int kc = r / 4;

  __shared__ bf16 smem[24576];

  const int tid = threadIdx.x;
  const int lane = tid & 63, wave = tid >> 6;
  const int wr = wave >> 1, wc = wave & 1;
  const int lr = lane & 15, lk = (lane >> 4) * 8, lg = (lane >> 4) * 4;

  const bf16* At = P + (long)b * NQ * SEQ + (long)row * 128 * SEQ + (long)kc * PHS_KC;
  const bf16* Bt = HT + (long)b * HIDDEN * SEQ + (long)col * 128 * SEQ + (long)kc * PHS_KC;

#define STAGE_PHS(buf, k0)                                                    \
  {                                                                           \
    bf16* dA = smem + (buf) * 4096;                                           \
    bf16* dB = smem + 12288 + (buf) * 4096;                                   \
    _Pragma("unroll") for (int h = 0; h < 2; ++h) {                           \
      const int cch = tid + h * 256;                                          \
      const int rr = cch >> 2, cc = (cch & 3) * 8;                            \
      GLOAD16(At + (long)rr * SEQ + (k0) + cc, (char*)dA + cch * 16);         \
      GLOAD16(Bt + (long)rr * SEQ + (k0) + cc, (char*)dB + cch * 16);         \
    }                                                                         \
  }

  const int nt = PHS_KC / 32;  // 64
  STAGE_PHS(0, 0);
  STAGE_PHS(1, 32);

  f32x4 acc[4][4] = {};
#pragma unroll 1
  for (int t = 0; t < nt; ++t) {
    FENCE;
    __builtin_amdgcn_s_barrier();
    FENCE;
    if (t + 2 < nt) {
      STAGE_PHS((t + 2) % 3, (t + 2) * 32);
      asm volatile("s_waitcnt vmcnt(8)" ::: "memory");
    } else if (t + 2 == nt) {
      asm volatile("s_waitcnt vmcnt(4)" ::: "memory");
    } else {
      asm volatile("s_waitcnt vmcnt(0)" ::: "memory");
    }
    __builtin_amdgcn_s_barrier();
    FENCE;
    const bf16* rA = smem + (t % 3) * 4096;
    const bf16* rB = smem + 12288 + (t % 3) * 4096;
    bf16x8 af[4], bfr[4];
#pragma unroll
    for (int m = 0; m < 4; ++m)
      af[m] = *reinterpret_cast<const bf16x8*>(&rA[(wr * 64 + m * 16 + lr) * 32 + lk]);
#pragma unroll
    for (int n = 0; n < 4; ++n)
      bfr[n] = *reinterpret_cast<const bf16x8*>(&rB[(wc * 64 + n * 16 + lr) * 32 + lk]);
    __builtin_amdgcn_s_setprio(1);
#pragma unroll
    for (int m = 0; m < 4; ++m)
#pragma unroll
      for (int n = 0; n < 4; ++n)
        acc[m][n] = __builtin_amdgcn_mfma_f32_16x16x32_bf16(af[m], bfr[n], acc[m][n], 0, 0, 0);
    __builtin_amdgcn_s_setprio(0);
  }
#undef STAGE_PHS

  FENCE;
  __builtin_amdgcn_s_barrier();
  FENCE;
#pragma unroll
  for (int m = 0; m < 4; ++m)
#pragma unroll
    for (int n = 0; n < 4; ++n)
#pragma unroll
      for (int j = 0; j < 4; ++j)
        smem[(wr * 64 + m * 16 + lg + j) * 128 + wc * 64 + n * 16 + lr] =
            (bf16)acc[m][n][j];
  __syncthreads();
  bf16* Co = Cp + ((long)kc * BATCH + b) * NQ * HIDDEN;
  const long rb = (long)row * 128, cb = (long)col * 128;
#pragma unroll
  for (int i = 0; i < 8; ++i) {
    const int ch = tid + i * 256;
    const int rr = ch >> 4;
    const int ce = (ch & 15) * 8;
    *reinterpret_cast<bf16x8*>(&Co[(rb + rr) * HIDDEN + cb + ce]) =
        *reinterpret_cast<const bf16x8*>(smem + ch * 8);
  }
}

// ctx1 = (sum of PHS_KS bf16 partials) / rowsum[row]   (fp32 accumulate)
__global__ __launch_bounds__(256) void k_reduceN(const bf16* __restrict__ p,
                                                 const float* __restrict__ rs,
                                                 bf16* __restrict__ out, int n8) {
  const long NB = (long)BATCH * NQ * HIDDEN;
  const int stride = gridDim.x * blockDim.x;
  for (int i = blockIdx.x * blockDim.x + threadIdx.x; i < n8; i += stride) {
    float acc[8] = {};
#pragma unroll
    for (int k = 0; k < PHS_KS; ++k) {
      bf16x8 v = reinterpret_cast<const bf16x8*>(p + k * NB)[i];
#pragma unroll
      for (int j = 0; j < 8; ++j) acc[j] += (float)v[j];
    }
    const float inv = 1.0f / rs[i / 96];  // 96 vec8-chunks per 768-col row
    bf16x8 o;
#pragma unroll
    for (int j = 0; j < 8; ++j) o[j] = (bf16)(acc[j] * inv);
    reinterpret_cast<bf16x8*>(out)[i] = o;
  }
}

// ---------------------------------------------------------------------------
extern "C" void kernel_launch(void* const* d_in, const int* in_sizes, int n_in,
                              void* d_out, int out_size, void* d_ws, size_t ws_size,
                              hipStream_t stream) {
  const float* hs = (const float*)d_in[0];    // [B,S,H]
  const float* qu = (const float*)d_in[1];    // [B,Q,H]
  const float* mask = (const float*)d_in[2];  // [B,S]
  const float* Wq = (const float*)d_in[3];
  const float* bq = (const float*)d_in[4];
  const float* Wk = (const float*)d_in[5];
  const float* Wv = (const float*)d_in[7];
  const float* bv = (const float*)d_in[8];
  float* out = (float*)d_out;  // [B,Q,H] fp32
  // bk (d_in[6]) adds a softmax-row-constant -> cancels exactly.

  const size_t HS_N = (size_t)BATCH * SEQ * HIDDEN;
  const size_t QU_N = (size_t)BATCH * NQ * HIDDEN;
  const size_t W_N = (size_t)HIDDEN * HIDDEN;
  const size_t P_N = (size_t)BATCH * NQ * SEQ;

  char* ws = (char*)d_ws;
  size_t off = 0;
  auto alloc = [&](size_t bytes) {
    char* p = ws + off;
    off += (bytes + 255) & ~(size_t)255;
    return p;
  };

  // regionA: hsb (live through scores) / PHS partials (after) — overlap
  char* regionA = alloc(HS_N * 2);
  bf16* hsb = (bf16*)regionA;
  bf16* Ppart = (bf16*)regionA;         // PHS_KS(4) * QU_N bf16 = 25.2 MB
  bf16* hsT = (bf16*)alloc(HS_N * 2);   // [B][H][S]
  bf16* Pr = (bf16*)alloc(P_N * 2);     // unnormalized probs exp(s+mb)
  bf16* qub = (bf16*)alloc(QU_N * 2);
  bf16* tmpb = (bf16*)alloc(QU_N * 2);  // folded query: qu.(Wq.Wk^T) + bq.Wk^T
  bf16* ctx1 = (bf16*)alloc(QU_N * 2);  // (P.hs)/rowsum
  bf16* Wkb = (bf16*)alloc(W_N * 2);
  bf16* Wqb = (bf16*)alloc(W_N * 2);
  bf16* WvT = (bf16*)alloc(W_N * 2);
  bf16* Mt = (bf16*)alloc(W_N * 2);     // Wk.Wq^T
  float* bqk = (float*)alloc(HIDDEN * 4);
  float* rspart = (float*)alloc((size_t)BATCH * NQ * 128 * 4);  // 2 MB
  float* rowsum = (float*)alloc((size_t)BATCH * NQ * 4);

  // 1) converts + fused hs prep
  k_cvt<<<dim3(1024), dim3(256), 0, stream>>>(qu, qub, (int)(QU_N / 4));
  k_cvt<<<dim3(576), dim3(256), 0, stream>>>(Wk, Wkb, (int)(W_N / 4));
  k_cvt<<<dim3(576), dim3(256), 0, stream>>>(Wq, Wqb, (int)(W_N / 4));
  k_transpose_w<<<dim3(24, 24), dim3(256), 0, stream>>>(Wv, WvT, HIDDEN, HIDDEN);
  k_cvt_hs_dual<<<dim3(12, 1024), dim3(256), 0, stream>>>(hs, hsb, hsT);
  k_gemv_bqk<<<dim3(768), dim3(64), 0, stream>>>(Wk, bq, bqk);

  // 2) Mt = Wk.Wq^T  [768x768]
  k_gemm_bt<bf16, 0><<<dim3(36), dim3(256), 0, stream>>>(
      Wkb, Wqb, Mt, nullptr, nullptr, nullptr, HIDDEN, HIDDEN, 1.0f, 6, 6, 0, 0, 0, 0);

  // 3) folded query: tmp = qub.Mt^T + bqk  [4096x768]
  k_gemm_bt<bf16, 0><<<dim3(192), dim3(256), 0, stream>>>(
      qub, Mt, tmpb, bqk, nullptr, nullptr, HIDDEN, HIDDEN, 1.0f, 6, 32, 0, 0, 0, 0);

  // 4) scores: Pr = exp(tmp.hsb^T/sqrt(H) + maskbias), rowsum partials
  const float qkscale = 1.0f / sqrtf((float)HIDDEN);
  k_gemm_bt<bf16, 1><<<dim3(2048), dim3(256), 0, stream>>>(
      tmpb, hsb, Pr, nullptr, mask, rspart, SEQ, HIDDEN, qkscale, 64, 8, 1,
      (long)NQ * HIDDEN, (long)SEQ * HIDDEN, (long)NQ * SEQ);
  k_rowsum<<<dim3(BATCH * NQ / 8), dim3(256), 0, stream>>>(rspart, rowsum);

  // 5) PHS partials: Ppart[kc] = P[:, kc-chunk] . hsT^T  (overwrites dead hsb)
  k_gemm_phs<<<dim3(6 * 8 * 4 * PHS_KS), dim3(256), 0, stream>>>(Pr, hsT, Ppart);

  // 6) ctx1 = (sum partials) / rowsum
  k_reduceN<<<dim3(1536), dim3(256), 0, stream>>>(Ppart, rowsum, ctx1, (int)(QU_N / 8));

  // 7) V-fold: out = ctx1.Wv + bv  (sum_j p = 1 makes +bv exact)
  k_gemm_bt<float, 0><<<dim3(192), dim3(256), 0, stream>>>(
      ctx1, WvT, out, bv, nullptr, nullptr, HIDDEN, HIDDEN, 1.0f, 6, 32, 0, 0, 0, 0);
}

// Round 10
// 238.425 us; speedup vs baseline: 1.1675x; 1.0813x over previous
//
#include <hip/hip_runtime.h>
#include <hip/hip_bf16.h>
#include <hip/hip_fp8.h>
#include <stdint.h>
#include <math.h>

#define HIDDEN 768
#define BATCH 4
#define SEQ 8192
#define NQ 1024
#define PHS_KS 4
#define PHS_KC (SEQ / PHS_KS)

typedef __bf16 bf16;
typedef unsigned char u8;
typedef __bf16 bf16x4 __attribute__((ext_vector_type(4)));
typedef __bf16 bf16x8 __attribute__((ext_vector_type(8)));
typedef float f32x4 __attribute__((ext_vector_type(4)));
typedef unsigned int u32x4 __attribute__((ext_vector_type(4)));

__device__ inline u8 to_fp8(float v) {
  return (u8)__hip_cvt_float_to_fp8(v, __HIP_SATFINITE, __HIP_E4M3);
}

// General bijective XCD-chunked block-id swizzle (m204 formula, any grid size).
__device__ inline int xcd_swz() {
  const unsigned n = gridDim.x, o = blockIdx.x;
  const unsigned q = n >> 3, r = n & 7;
  const unsigned x = o & 7, k = o >> 3;
  return (int)((x < r ? x * (q + 1) : r * (q + 1) + (x - r) * q) + k);
}

#define GLOAD16(gptr, lptr)                                                   \
  __builtin_amdgcn_global_load_lds(                                           \
      (const __attribute__((address_space(1))) void*)(gptr),                  \
      (__attribute__((address_space(3))) void*)(lptr), 16, 0, 0)

#define FENCE asm volatile("" ::: "memory")

// ---------------------------------------------------------------------------
// fp32 -> bf16 elementwise convert (float4 vectorized, grid-stride)
__global__ __launch_bounds__(256) void k_cvt(const float* __restrict__ in,
                                             bf16* __restrict__ out, int n4) {
  int stride = gridDim.x * blockDim.x;
  for (int i = blockIdx.x * blockDim.x + threadIdx.x; i < n4; i += stride) {
    float4 v = reinterpret_cast<const float4*>(in)[i];
    bf16x4 o = {(bf16)v.x, (bf16)v.y, (bf16)v.z, (bf16)v.w};
    reinterpret_cast<bf16x4*>(out)[i] = o;
  }
}

// two fp32->bf16 converts in one launch (blockIdx.y selects the pair member)
__global__ __launch_bounds__(256) void k_cvt2(const float* __restrict__ a,
                                              bf16* __restrict__ oa,
                                              const float* __restrict__ b,
                                              bf16* __restrict__ ob, int n4) {
  const float* in = blockIdx.y ? b : a;
  bf16* out = blockIdx.y ? ob : oa;
  int stride = gridDim.x * blockDim.x;
  for (int i = blockIdx.x * blockDim.x + threadIdx.x; i < n4; i += stride) {
    float4 v = reinterpret_cast<const float4*>(in)[i];
    bf16x4 o = {(bf16)v.x, (bf16)v.y, (bf16)v.z, (bf16)v.w};
    reinterpret_cast<bf16x4*>(out)[i] = o;
  }
}

// ---------------------------------------------------------------------------
// [R][C] fp32 -> [C][R] bf16 tiled transpose-convert (weights).
__global__ __launch_bounds__(256) void k_transpose_w(
    const float* __restrict__ in, bf16* __restrict__ out, int R, int C) {
  __shared__ float tile[32][33];
  const int c0 = blockIdx.x * 32, r0 = blockIdx.y * 32;
  const int tx = threadIdx.x & 31, ty = threadIdx.x >> 5;  // 32 x 8
#pragma unroll
  for (int i = 0; i < 32; i += 8)
    tile[ty + i][tx] = in[(long)(r0 + ty + i) * C + (c0 + tx)];
  __syncthreads();
#pragma unroll
  for (int i = 0; i < 32; i += 8)
    out[(long)(c0 + ty + i) * R + (r0 + tx)] = (bf16)tile[tx][ty + i];
}

// ---------------------------------------------------------------------------
// Fused: hs fp32 [B*S][H] -> hsb bf16 (same layout) + hsT fp8 e4m3 [B][H][S].
__global__ __launch_bounds__(256) void k_cvt_hs_dual(const float* __restrict__ hs,
                                                     bf16* __restrict__ hsb,
                                                     u8* __restrict__ hsT) {
  __shared__ float T[32][65];
  const int h0 = blockIdx.x * 64;
  const int s0g = blockIdx.y * 32;  // global row in [0, B*S)
  const int b = s0g >> 13;          // / 8192
  const int sIn = s0g & 8191;
  const int t = threadIdx.x;
  const int r = t >> 3, c = (t & 7) * 8;

  const float* src = hs + (long)(s0g + r) * HIDDEN + h0 + c;
  float4 v0 = *reinterpret_cast<const float4*>(src);
  float4 v1 = *reinterpret_cast<const float4*>(src + 4);
  T[r][c + 0] = v0.x; T[r][c + 1] = v0.y; T[r][c + 2] = v0.z; T[r][c + 3] = v0.w;
  T[r][c + 4] = v1.x; T[r][c + 5] = v1.y; T[r][c + 6] = v1.z; T[r][c + 7] = v1.w;

  bf16x8 o = {(bf16)v0.x, (bf16)v0.y, (bf16)v0.z, (bf16)v0.w,
              (bf16)v1.x, (bf16)v1.y, (bf16)v1.z, (bf16)v1.w};
  *reinterpret_cast<bf16x8*>(hsb + (long)(s0g + r) * HIDDEN + h0 + c) = o;

  __syncthreads();
  const int hh = t >> 2, ss = (t & 3) * 8;
  unsigned long long v8 = 0;
#pragma unroll
  for (int k = 0; k < 8; ++k)
    v8 |= (unsigned long long)to_fp8(T[ss + k][hh]) << (8 * k);
  *reinterpret_cast<unsigned long long*>(
      hsT + ((long)b * HIDDEN + h0 + hh) * SEQ + sIn + ss) = v8;
}

// bqk[h] = sum_d bq[d] * Wk[h][d]
__global__ __launch_bounds__(64) void k_gemv_bqk(const float* __restrict__ Wk,
                                                 const float* __restrict__ bq,
                                                 float* __restrict__ bqk) {
  const int h = blockIdx.x, l = threadIdx.x;
  float s = 0.0f;
#pragma unroll
  for (int d = l; d < HIDDEN; d += 64) s += bq[d] * Wk[(long)h * HIDDEN + d];
#pragma unroll
  for (int o = 32; o > 0; o >>= 1) s += __shfl_xor(s, o);
  if (l == 0) bqk[h] = s;
}

// ---------------------------------------------------------------------------
// C = (A.B^T)*scale + bias[col]                       (MODE 0: bf16 or fp32 out)
//   = exp((A.B^T)*scale + maskbias[z][col]) as FP8    (MODE 1: OUT=u8, + rowsums)
// 128x128 tile, BK=32, 4 waves, 16x16x32 bf16 MFMA, global_load_lds w16.
// K-loop (round-7 verified): 2 raw barriers, prefetch between them,
// s_waitcnt vmcnt(4) -> next tile's 4 loads stay in flight across the barrier.
template <typename OUT, int MODE>
__global__ __launch_bounds__(256) void k_gemm_bt(
    const bf16* __restrict__ A, const bf16* __restrict__ B, OUT* __restrict__ C,
    const float* __restrict__ bias, const float* __restrict__ mask,
    float* __restrict__ rspart, int N, int K, float scale,
    int nx, int ny, int rowfast, long strA, long strB, long strC) {
  const int id = xcd_swz();
  int col, row, z;
  if (rowfast) {
    row = id % ny; col = (id / ny) % nx; z = id / (ny * nx);
  } else {
    col = id % nx; row = (id / nx) % ny; z = id / (nx * ny);
  }

  __shared__ bf16 smem[16384];  // A dbuf @0, B dbuf @8192; epilogue: C tile

  const int tid = threadIdx.x;
  const int lane = tid & 63, wave = tid >> 6;
  const int wr = wave >> 1, wc = wave & 1;
  const int lr = lane & 15, lk = (lane >> 4) * 8, lg = (lane >> 4) * 4;

  const bf16* At = A + (long)z * strA + (long)row * 128 * K;
  const bf16* Bt = B + (long)z * strB + (long)col * 128 * K;

#define STAGE_TILE(buf, k0)                                                   \
  {                                                                           \
    bf16* dA = smem + (buf) * 4096;                                           \
    bf16* dB = smem + 8192 + (buf) * 4096;                                    \
    _Pragma("unroll") for (int h = 0; h < 2; ++h) {                           \
      const int cch = tid + h * 256;                                          \
      const int rr = cch >> 2, cc = (cch & 3) * 8;                            \
      GLOAD16(At + (long)rr * K + (k0) + cc, (char*)dA + cch * 16);           \
      GLOAD16(Bt + (long)rr * K + (k0) + cc, (char*)dB + cch * 16);           \
    }                                                                         \
  }

  STAGE_TILE(0, 0);

  f32x4 acc[4][4] = {};
  const int nt = K / 32;
  int cur = 0;
#pragma unroll 1
  for (int t = 0; t < nt; ++t) {
    FENCE;
    __builtin_amdgcn_s_barrier();  // reads of tile t-1 done -> its buf free
    FENCE;
    if (t + 1 < nt) {
      STAGE_TILE(cur ^ 1, (t + 1) * 32);
      asm volatile("s_waitcnt vmcnt(4)" ::: "memory");  // tile t landed; t+1 in flight
    } else {
      asm volatile("s_waitcnt vmcnt(0)" ::: "memory");
    }
    __builtin_amdgcn_s_barrier();  // tile t resident for every thread
    FENCE;
    const bf16* rA = smem + cur * 4096;
    const bf16* rB = smem + 8192 + cur * 4096;
    bf16x8 af[4], bfr[4];
#pragma unroll
    for (int m = 0; m < 4; ++m)
      af[m] = *reinterpret_cast<const bf16x8*>(&rA[(wr * 64 + m * 16 + lr) * 32 + lk]);
#pragma unroll
    for (int n = 0; n < 4; ++n)
      bfr[n] = *reinterpret_cast<const bf16x8*>(&rB[(wc * 64 + n * 16 + lr) * 32 + lk]);
    __builtin_amdgcn_s_setprio(1);
#pragma unroll
    for (int m = 0; m < 4; ++m)
#pragma unroll
      for (int n = 0; n < 4; ++n)
        acc[m][n] = __builtin_amdgcn_mfma_f32_16x16x32_bf16(af[m], bfr[n], acc[m][n], 0, 0, 0);
    __builtin_amdgcn_s_setprio(0);
    cur ^= 1;
  }
#undef STAGE_TILE

  if constexpr (__is_same(OUT, float)) {
    // direct fp32 stores (64B segments)
    float* Cb = (float*)C + (long)z * strC;
#pragma unroll
    for (int m = 0; m < 4; ++m)
#pragma unroll
      for (int n = 0; n < 4; ++n) {
        const int gc = col * 128 + wc * 64 + n * 16 + lr;
        const float bv = bias ? bias[gc] : 0.0f;
#pragma unroll
        for (int j = 0; j < 4; ++j) {
          const int gr = row * 128 + wr * 64 + m * 16 + lg + j;
          Cb[(long)gr * N + gc] = acc[m][n][j] * scale + bv;
        }
      }
  } else if constexpr (MODE == 1) {
    // fp8 output: exp(v*scale + maskbias), rowsum partials, LDS-bounced stores
    FENCE;
    __builtin_amdgcn_s_barrier();  // staging LDS now reused as C tile (u8)
    FENCE;
    u8* sm8 = (u8*)smem;
    float rsv[4][4];
#pragma unroll
    for (int m = 0; m < 4; ++m)
#pragma unroll
      for (int j = 0; j < 4; ++j) rsv[m][j] = 0.0f;
#pragma unroll
    for (int m = 0; m < 4; ++m)
#pragma unroll
      for (int n = 0; n < 4; ++n) {
        const int gc = col * 128 + wc * 64 + n * 16 + lr;
        const float mbv = (1.0f - mask[(long)z * SEQ + gc]) * -10000.0f;
#pragma unroll
        for (int j = 0; j < 4; ++j) {
          const float v = expf(acc[m][n][j] * scale + mbv);
          rsv[m][j] += v;
          sm8[(wr * 64 + m * 16 + lg + j) * 128 + wc * 64 + n * 16 + lr] = to_fp8(v);
        }
      }
#pragma unroll
    for (int m = 0; m < 4; ++m)
#pragma unroll
      for (int j = 0; j < 4; ++j) {
        float v = rsv[m][j];
        v += __shfl_xor(v, 1); v += __shfl_xor(v, 2);
        v += __shfl_xor(v, 4); v += __shfl_xor(v, 8);
        if ((lane & 15) == 0) {
          const int gr = row * 128 + wr * 64 + m * 16 + lg + j;
          rspart[((long)z * NQ + gr) * 128 + col * 2 + wc] = v;
        }
      }
    __syncthreads();
    u8* Cb = (u8*)C + (long)z * strC;
    const long rb = (long)row * 128, cb = (long)col * 128;
#pragma unroll
    for (int i = 0; i < 4; ++i) {
      const int ch = tid + i * 256;  // 1024 chunks of 16B = 128x128 u8
      const int rr = ch >> 3;        // 8 chunks per 128-byte row
      const int ce = (ch & 7) * 16;
      *reinterpret_cast<u32x4*>(&Cb[(rb + rr) * (long)N + cb + ce]) =
          *reinterpret_cast<const u32x4*>(sm8 + ch * 16);
    }
  } else {
    // bf16 output with bias, LDS-bounced stores
    FENCE;
    __builtin_amdgcn_s_barrier();
    FENCE;
#pragma unroll
    for (int m = 0; m < 4; ++m)
#pragma unroll
      for (int n = 0; n < 4; ++n) {
        const int gc = col * 128 + wc * 64 + n * 16 + lr;
        const float bv = bias ? bias[gc] : 0.0f;
#pragma unroll
        for (int j = 0; j < 4; ++j)
          smem[(wr * 64 + m * 16 + lg + j) * 128 + wc * 64 + n * 16 + lr] =
              (bf16)(acc[m][n][j] * scale + bv);
      }
    __syncthreads();
    OUT* Cb = C + (long)z * strC;
    const long rb = (long)row * 128, cb = (long)col * 128;
#pragma unroll
    for (int i = 0; i < 8; ++i) {
      const int ch = tid + i * 256;
      const int rr = ch >> 4;
      const int ce = (ch & 15) * 8;
      *reinterpret_cast<bf16x8*>(&Cb[(rb + rr) * N + cb + ce]) =
          *reinterpret_cast<const bf16x8*>(smem + ch * 8);
    }
  }
}

// rowsum[row] = sum of 128 partial slots (deterministic reduce)
__global__ __launch_bounds__(256) void k_rowsum(const float* __restrict__ rp,
                                                float* __restrict__ rs) {
  const int t = threadIdx.x;
  const int row = blockIdx.x * 8 + (t >> 5);
  const int s = t & 31;
  const float* base = rp + (long)row * 128;
  float v = base[s] + base[s + 32] + base[s + 64] + base[s + 96];
  v += __shfl_xor(v, 1); v += __shfl_xor(v, 2); v += __shfl_xor(v, 4);
  v += __shfl_xor(v, 8); v += __shfl_xor(v, 16);
  if (s == 0) rs[row] = v;
}

// ---------------------------------------------------------------------------
// PHS split-K partial GEMM (FP8): Cpart[kc][b,q,:] = P8[b,q-tile,kc] . hsT8^T
// P8: [B][NQ][SEQ] e4m3, hsT8: [B][HIDDEN][SEQ] e4m3, partials bf16.
// 128x128 tile, BK=32, mfma_f32_16x16x32_fp8_fp8 (i64 frags, 8 bytes/lane,
// lane -> row=l&15, k=(l>>4)*8+j — same K-decomposition as the verified bf16).
// Staging: 2 gloads/thread -> vmcnt(2) counted wait. LDS 32KB (5 blocks/CU).
__global__ __launch_bounds__(256) void k_gemm_phs(const u8* __restrict__ P,
                                                  const u8* __restrict__ HT,
                                                  bf16* __restrict__ Cp) {
  const int id = xcd_swz();
  const int col = id % 6;
  int r = id / 6;
  const int row = r % 8;
  r /= 8;
  const int b = r % 4;
  const int kc = r / 4;

  __shared__ char smem[32768];  // staging: A 2x4K @0, B 2x4K @8192; epilogue: bf16 tile
  u8* sm8 = (u8*)smem;

  const int tid = threadIdx.x;
  const int lane = tid & 63, wave = tid >> 6;
  const int wr = wave >> 1, wc = wave & 1;
  const int lr = lane & 15, l16 = lane >> 4;
  const int lg = l16 * 4;

  const u8* At = P + (long)b * NQ * SEQ + (long)row * 128 * SEQ + (long)kc * PHS_KC;
  const u8* Bt = HT + ((long)b * HIDDEN + (long)col * 128) * SEQ + (long)kc * PHS_KC;

#define STAGE_P8(buf, k0)                                                     \
  {                                                                           \
    u8* dA = sm8 + (buf) * 4096;                                              \
    u8* dB = sm8 + 8192 + (buf) * 4096;                                       \
    const int rr = tid >> 1, cc = (tid & 1) * 16;                             \
    GLOAD16(At + (long)rr * SEQ + (k0) + cc, dA + tid * 16);                  \
    GLOAD16(Bt + (long)rr * SEQ + (k0) + cc, dB + tid * 16);                  \
  }

  const int nt = PHS_KC / 32;  // 64
  STAGE_P8(0, 0);

  f32x4 acc[4][4] = {};
#pragma unroll 1
  for (int t = 0; t < nt; ++t) {
    FENCE;
    __builtin_amdgcn_s_barrier();
    FENCE;
    if (t + 1 < nt) {
      STAGE_P8((t + 1) & 1, (t + 1) * 32);
      asm volatile("s_waitcnt vmcnt(2)" ::: "memory");
    } else {
      asm volatile("s_waitcnt vmcnt(0)" ::: "memory");
    }
    __builtin_amdgcn_s_barrier();
    FENCE;
    const u8* rA = sm8 + (t & 1) * 4096;
    const u8* rB = sm8 + 8192 + (t & 1) * 4096;
    long af[4], bfr[4];
#pragma unroll
    for (int m = 0; m < 4; ++m)
      af[m] = *reinterpret_cast<const long*>(rA + (wr * 64 + m * 16 + lr) * 32 + l16 * 8);
#pragma unroll
    for (int n = 0; n < 4; ++n)
      bfr[n] = *reinterpret_cast<const long*>(rB + (wc * 64 + n * 16 + lr) * 32 + l16 * 8);
    __builtin_amdgcn_s_setprio(1);
#pragma unroll
    for (int m = 0; m < 4; ++m)
#pragma unroll
      for (int n = 0; n < 4; ++n)
        acc[m][n] = __builtin_amdgcn_mfma_f32_16x16x32_fp8_fp8(af[m], bfr[n], acc[m][n], 0, 0, 0);
    __builtin_amdgcn_s_setprio(0);
  }
#undef STAGE_P8

  FENCE;
  __builtin_amdgcn_s_barrier();
  FENCE;
  bf16* smb = (bf16*)smem;
#pragma unroll
  for (int m = 0; m < 4; ++m)
#pragma unroll
    for (int n = 0; n < 4; ++n)
#pragma unroll
      for (int j = 0; j < 4; ++j)
        smb[(wr * 64 + m * 16 + lg + j) * 128 + wc * 64 + n * 16 + lr] =
            (bf16)acc[m][n][j];
  __syncthreads();
  bf16* Co = Cp + ((long)kc * BATCH + b) * NQ * HIDDEN;
  const long rb = (long)row * 128, cb = (long)col * 128;
#pragma unroll
  for (int i = 0; i < 8; ++i) {
    const int ch = tid + i * 256;
    const int rr = ch >> 4;
    const int ce = (ch & 15) * 8;
    *reinterpret_cast<bf16x8*>(&Co[(rb + rr) * HIDDEN + cb + ce]) =
        *reinterpret_cast<const bf16x8*>(smb + ch * 8);
  }
}

// ctx1 = (sum of PHS_KS bf16 partials) / rowsum[row]   (fp32 accumulate)
__global__ __launch_bounds__(256) void k_reduceN(const bf16* __restrict__ p,
                                                 const float* __restrict__ rs,
                                                 bf16* __restrict__ out, int n8) {
  const long NB = (long)BATCH * NQ * HIDDEN;
  const int stride = gridDim.x * blockDim.x;
  for (int i = blockIdx.x * blockDim.x + threadIdx.x; i < n8; i += stride) {
    float acc[8] = {};
#pragma unroll
    for (int k = 0; k < PHS_KS; ++k) {
      bf16x8 v = reinterpret_cast<const bf16x8*>(p + k * NB)[i];
#pragma unroll
      for (int j = 0; j < 8; ++j) acc[j] += (float)v[j];
    }
    const float inv = 1.0f / rs[i / 96];  // 96 vec8-chunks per 768-col row
    bf16x8 o;
#pragma unroll
    for (int j = 0; j < 8; ++j) o[j] = (bf16)(acc[j] * inv);
    reinterpret_cast<bf16x8*>(out)[i] = o;
  }
}

// ---------------------------------------------------------------------------
extern "C" void kernel_launch(void* const* d_in, const int* in_sizes, int n_in,
                              void* d_out, int out_size, void* d_ws, size_t ws_size,
                              hipStream_t stream) {
  const float* hs = (const float*)d_in[0];    // [B,S,H]
  const float* qu = (const float*)d_in[1];    // [B,Q,H]
  const float* mask = (const float*)d_in[2];  // [B,S]
  const float* Wq = (const float*)d_in[3];
  const float* bq = (const float*)d_in[4];
  const float* Wk = (const float*)d_in[5];
  const float* Wv = (const float*)d_in[7];
  const float* bv = (const float*)d_in[8];
  float* out = (float*)d_out;  // [B,Q,H] fp32
  // bk (d_in[6]) adds a softmax-row-constant -> cancels exactly.

  const size_t HS_N = (size_t)BATCH * SEQ * HIDDEN;
  const size_t QU_N = (size_t)BATCH * NQ * HIDDEN;
  const size_t W_N = (size_t)HIDDEN * HIDDEN;
  const size_t P_N = (size_t)BATCH * NQ * SEQ;

  char* ws = (char*)d_ws;
  size_t off = 0;
  auto alloc = [&](size_t bytes) {
    char* p = ws + off;
    off += (bytes + 255) & ~(size_t)255;
    return p;
  };

  // regionA: hsb (live through scores) / PHS partials (after) — overlap
  char* regionA = alloc(HS_N * 2);
  bf16* hsb = (bf16*)regionA;
  bf16* Ppart = (bf16*)regionA;        // PHS_KS(4) * QU_N bf16 = 25.2 MB
  u8* hsT8 = (u8*)alloc(HS_N);         // [B][H][S] fp8 e4m3
  u8* Pr = (u8*)alloc(P_N);            // unnormalized probs exp(s+mb), fp8
  bf16* qub = (bf16*)alloc(QU_N * 2);
  bf16* tmpb = (bf16*)alloc(QU_N * 2); // folded query: qu.(Wq.Wk^T) + bq.Wk^T
  bf16* ctx1 = (bf16*)alloc(QU_N * 2); // (P.hs)/rowsum
  bf16* Wkb = (bf16*)alloc(W_N * 2);
  bf16* Wqb = (bf16*)alloc(W_N * 2);
  bf16* WvT = (bf16*)alloc(W_N * 2);
  bf16* Mt = (bf16*)alloc(W_N * 2);    // Wk.Wq^T
  float* bqk = (float*)alloc(HIDDEN * 4);
  float* rspart = (float*)alloc((size_t)BATCH * NQ * 128 * 4);  // 2 MB
  float* rowsum = (float*)alloc((size_t)BATCH * NQ * 4);

  // 1) converts + fused hs prep
  k_cvt<<<dim3(1024), dim3(256), 0, stream>>>(qu, qub, (int)(QU_N / 4));
  k_cvt2<<<dim3(288, 2), dim3(256), 0, stream>>>(Wk, Wkb, Wq, Wqb, (int)(W_N / 4));
  k_transpose_w<<<dim3(24, 24), dim3(256), 0, stream>>>(Wv, WvT, HIDDEN, HIDDEN);
  k_cvt_hs_dual<<<dim3(12, 1024), dim3(256), 0, stream>>>(hs, hsb, hsT8);
  k_gemv_bqk<<<dim3(768), dim3(64), 0, stream>>>(Wk, bq, bqk);

  // 2) Mt = Wk.Wq^T  [768x768]
  k_gemm_bt<bf16, 0><<<dim3(36), dim3(256), 0, stream>>>(
      Wkb, Wqb, Mt, nullptr, nullptr, nullptr, HIDDEN, HIDDEN, 1.0f, 6, 6, 0, 0, 0, 0);

  // 3) folded query: tmp = qub.Mt^T + bqk  [4096x768]
  k_gemm_bt<bf16, 0><<<dim3(192), dim3(256), 0, stream>>>(
      qub, Mt, tmpb, bqk, nullptr, nullptr, HIDDEN, HIDDEN, 1.0f, 6, 32, 0, 0, 0, 0);

  // 4) scores: Pr(fp8) = exp(tmp.hsb^T/sqrt(H) + maskbias), rowsum partials
  const float qkscale = 1.0f / sqrtf((float)HIDDEN);
  k_gemm_bt<u8, 1><<<dim3(2048), dim3(256), 0, stream>>>(
      tmpb, hsb, Pr, nullptr, mask, rspart, SEQ, HIDDEN, qkscale, 64, 8, 1,
      (long)NQ * HIDDEN, (long)SEQ * HIDDEN, (long)NQ * SEQ);
  k_rowsum<<<dim3(BATCH * NQ / 8), dim3(256), 0, stream>>>(rspart, rowsum);

  // 5) PHS partials (fp8 MFMA): Ppart[kc] = P8[:, kc-chunk] . hsT8^T
  k_gemm_phs<<<dim3(6 * 8 * 4 * PHS_KS), dim3(256), 0, stream>>>(Pr, hsT8, Ppart);

  // 6) ctx1 = (sum partials) / rowsum
  k_reduceN<<<dim3(1536), dim3(256), 0, stream>>>(Ppart, rowsum, ctx1, (int)(QU_N / 8));

  // 7) V-fold: out = ctx1.Wv + bv  (sum_j p = 1 makes +bv exact)
  k_gemm_bt<float, 0><<<dim3(192), dim3(256), 0, stream>>>(
      ctx1, WvT, out, bv, nullptr, nullptr, HIDDEN, HIDDEN, 1.0f, 6, 32, 0, 0, 0, 0);
}

// Round 11
// 234.152 us; speedup vs baseline: 1.1888x; 1.0182x over previous
//
#include <hip/hip_runtime.h>
#include <hip/hip_bf16.h>
#include <hip/hip_fp8.h>
#include <stdint.h>
#include <math.h>

#define HIDDEN 768
#define BATCH 4
#define SEQ 8192
#define NQ 1024
#define PHS_KS 4
#define PHS_KC (SEQ / PHS_KS)

typedef __bf16 bf16;
typedef unsigned char u8;
typedef __bf16 bf16x4 __attribute__((ext_vector_type(4)));
typedef __bf16 bf16x8 __attribute__((ext_vector_type(8)));
typedef float f32x4 __attribute__((ext_vector_type(4)));
typedef unsigned int u32x4 __attribute__((ext_vector_type(4)));

#define L2E 1.44269504088896f

#if __has_builtin(__builtin_amdgcn_exp2f)
#define EXP2(x) __builtin_amdgcn_exp2f(x)
#else
#define EXP2(x) exp2f(x)
#endif

__device__ inline u8 to_fp8(float v) {
  return (u8)__hip_cvt_float_to_fp8(v, __HIP_SATFINITE, __HIP_E4M3);
}

// General bijective XCD-chunked block-id swizzle (m204 formula, any grid size).
__device__ inline int xcd_swz() {
  const unsigned n = gridDim.x, o = blockIdx.x;
  const unsigned q = n >> 3, r = n & 7;
  const unsigned x = o & 7, k = o >> 3;
  return (int)((x < r ? x * (q + 1) : r * (q + 1) + (x - r) * q) + k);
}

#define GLOAD16(gptr, lptr)                                                   \
  __builtin_amdgcn_global_load_lds(                                           \
      (const __attribute__((address_space(1))) void*)(gptr),                  \
      (__attribute__((address_space(3))) void*)(lptr), 16, 0, 0)

#define FENCE asm volatile("" ::: "memory")

// ---------------------------------------------------------------------------
// Fused prep: y=0 qu cvt, y=1 Wk+Wq cvt, y=2 Wv transpose-cvt, y=3 bqk gemv.
__global__ __launch_bounds__(256) void k_prep(
    const float* __restrict__ qu, bf16* __restrict__ qub,
    const float* __restrict__ Wk, bf16* __restrict__ Wkb,
    const float* __restrict__ Wq, bf16* __restrict__ Wqb,
    const float* __restrict__ Wv, bf16* __restrict__ WvT,
    const float* __restrict__ bq, float* __restrict__ bqk) {
  __shared__ float shm[32 * 33];
  const int t = threadIdx.x;
  const int y = blockIdx.y;

  if (y == 0) {  // qu fp32 -> bf16, 786432 float4s, grid-stride over 576 blocks
    const int n4 = (int)((size_t)BATCH * NQ * HIDDEN / 4);
    const int stride = gridDim.x * 256;
    for (int i = blockIdx.x * 256 + t; i < n4; i += stride) {
      float4 v = reinterpret_cast<const float4*>(qu)[i];
      bf16x4 o = {(bf16)v.x, (bf16)v.y, (bf16)v.z, (bf16)v.w};
      reinterpret_cast<bf16x4*>(qub)[i] = o;
    }
  } else if (y == 1) {  // Wk (x<288) / Wq (x>=288) cvt
    const int n4 = HIDDEN * HIDDEN / 4;
    const float* in = blockIdx.x < 288 ? Wk : Wq;
    bf16* out = blockIdx.x < 288 ? Wkb : Wqb;
    const int xb = blockIdx.x < 288 ? blockIdx.x : blockIdx.x - 288;
    for (int i = xb * 256 + t; i < n4; i += 288 * 256) {
      float4 v = reinterpret_cast<const float4*>(in)[i];
      bf16x4 o = {(bf16)v.x, (bf16)v.y, (bf16)v.z, (bf16)v.w};
      reinterpret_cast<bf16x4*>(out)[i] = o;
    }
  } else if (y == 2) {  // Wv [H][D] -> WvT [D][H] bf16 (576 = 24x24 tiles)
    const int c0 = (blockIdx.x % 24) * 32, r0 = (blockIdx.x / 24) * 32;
    const int tx = t & 31, ty = t >> 5;
#pragma unroll
    for (int i = 0; i < 32; i += 8)
      shm[(ty + i) * 33 + tx] = Wv[(long)(r0 + ty + i) * HIDDEN + (c0 + tx)];
    __syncthreads();
#pragma unroll
    for (int i = 0; i < 32; i += 8)
      WvT[(long)(c0 + ty + i) * HIDDEN + (r0 + tx)] = (bf16)shm[tx * 33 + ty + i];
  } else {  // bqk[h] = sum_d bq[d]*Wk[h][d]; 192 blocks x 4 waves = 768 h
    if (blockIdx.x >= 192) return;
    const int h = blockIdx.x * 4 + (t >> 6);
    const int l = t & 63;
    float s = 0.0f;
#pragma unroll
    for (int d = l; d < HIDDEN; d += 64) s += bq[d] * Wk[(long)h * HIDDEN + d];
#pragma unroll
    for (int o = 32; o > 0; o >>= 1) s += __shfl_xor(s, o);
    if (l == 0) bqk[h] = s;
  }
}

// ---------------------------------------------------------------------------
// Fused: hs fp32 [B*S][H] -> hsb bf16 (same layout) + hsT fp8 e4m3 [B][H][S].
__global__ __launch_bounds__(256) void k_cvt_hs_dual(const float* __restrict__ hs,
                                                     bf16* __restrict__ hsb,
                                                     u8* __restrict__ hsT) {
  __shared__ float T[32][65];
  const int h0 = blockIdx.x * 64;
  const int s0g = blockIdx.y * 32;  // global row in [0, B*S)
  const int b = s0g >> 13;          // / 8192
  const int sIn = s0g & 8191;
  const int t = threadIdx.x;
  const int r = t >> 3, c = (t & 7) * 8;

  const float* src = hs + (long)(s0g + r) * HIDDEN + h0 + c;
  float4 v0 = *reinterpret_cast<const float4*>(src);
  float4 v1 = *reinterpret_cast<const float4*>(src + 4);
  T[r][c + 0] = v0.x; T[r][c + 1] = v0.y; T[r][c + 2] = v0.z; T[r][c + 3] = v0.w;
  T[r][c + 4] = v1.x; T[r][c + 5] = v1.y; T[r][c + 6] = v1.z; T[r][c + 7] = v1.w;

  bf16x8 o = {(bf16)v0.x, (bf16)v0.y, (bf16)v0.z, (bf16)v0.w,
              (bf16)v1.x, (bf16)v1.y, (bf16)v1.z, (bf16)v1.w};
  *reinterpret_cast<bf16x8*>(hsb + (long)(s0g + r) * HIDDEN + h0 + c) = o;

  __syncthreads();
  const int hh = t >> 2, ss = (t & 3) * 8;
  unsigned long long v8 = 0;
#pragma unroll
  for (int k = 0; k < 8; ++k)
    v8 |= (unsigned long long)to_fp8(T[ss + k][hh]) << (8 * k);
  *reinterpret_cast<unsigned long long*>(
      hsT + ((long)b * HIDDEN + h0 + hh) * SEQ + sIn + ss) = v8;
}

// ---------------------------------------------------------------------------
// C = (A.B^T)*scale + bias[col]                       (MODE 0: bf16 or fp32 out)
//   = exp((A.B^T)*scale + maskbias[z][col]) as FP8    (MODE 1: OUT=u8, + rowsums)
// 128x128 tile, BK=32, 4 waves, 16x16x32 bf16 MFMA, global_load_lds w16.
// K-loop (round-7 verified): 2 raw barriers, prefetch between them,
// s_waitcnt vmcnt(4) -> next tile's 4 loads stay in flight across the barrier.
template <typename OUT, int MODE>
__global__ __launch_bounds__(256) void k_gemm_bt(
    const bf16* __restrict__ A, const bf16* __restrict__ B, OUT* __restrict__ C,
    const float* __restrict__ bias, const float* __restrict__ mask,
    float* __restrict__ rspart, int N, int K, float scale,
    int nx, int ny, int rowfast, long strA, long strB, long strC) {
  const int id = xcd_swz();
  int col, row, z;
  if (rowfast) {
    row = id % ny; col = (id / ny) % nx; z = id / (ny * nx);
  } else {
    col = id % nx; row = (id / nx) % ny; z = id / (nx * ny);
  }

  __shared__ bf16 smem[16384];  // A dbuf @0, B dbuf @8192; epilogue: C tile

  const int tid = threadIdx.x;
  const int lane = tid & 63, wave = tid >> 6;
  const int wr = wave >> 1, wc = wave & 1;
  const int lr = lane & 15, lk = (lane >> 4) * 8, lg = (lane >> 4) * 4;

  const bf16* At = A + (long)z * strA + (long)row * 128 * K;
  const bf16* Bt = B + (long)z * strB + (long)col * 128 * K;

#define STAGE_TILE(buf, k0)                                                   \
  {                                                                           \
    bf16* dA = smem + (buf) * 4096;                                           \
    bf16* dB = smem + 8192 + (buf) * 4096;                                    \
    _Pragma("unroll") for (int h = 0; h < 2; ++h) {                           \
      const int cch = tid + h * 256;                                          \
      const int rr = cch >> 2, cc = (cch & 3) * 8;                            \
      GLOAD16(At + (long)rr * K + (k0) + cc, (char*)dA + cch * 16);           \
      GLOAD16(Bt + (long)rr * K + (k0) + cc, (char*)dB + cch * 16);           \
    }                                                                         \
  }

  STAGE_TILE(0, 0);

  f32x4 acc[4][4] = {};
  const int nt = K / 32;
  int cur = 0;
#pragma unroll 1
  for (int t = 0; t < nt; ++t) {
    FENCE;
    __builtin_amdgcn_s_barrier();  // reads of tile t-1 done -> its buf free
    FENCE;
    if (t + 1 < nt) {
      STAGE_TILE(cur ^ 1, (t + 1) * 32);
      asm volatile("s_waitcnt vmcnt(4)" ::: "memory");  // tile t landed; t+1 in flight
    } else {
      asm volatile("s_waitcnt vmcnt(0)" ::: "memory");
    }
    __builtin_amdgcn_s_barrier();  // tile t resident for every thread
    FENCE;
    const bf16* rA = smem + cur * 4096;
    const bf16* rB = smem + 8192 + cur * 4096;
    bf16x8 af[4], bfr[4];
#pragma unroll
    for (int m = 0; m < 4; ++m)
      af[m] = *reinterpret_cast<const bf16x8*>(&rA[(wr * 64 + m * 16 + lr) * 32 + lk]);
#pragma unroll
    for (int n = 0; n < 4; ++n)
      bfr[n] = *reinterpret_cast<const bf16x8*>(&rB[(wc * 64 + n * 16 + lr) * 32 + lk]);
    __builtin_amdgcn_s_setprio(1);
#pragma unroll
    for (int m = 0; m < 4; ++m)
#pragma unroll
      for (int n = 0; n < 4; ++n)
        acc[m][n] = __builtin_amdgcn_mfma_f32_16x16x32_bf16(af[m], bfr[n], acc[m][n], 0, 0, 0);
    __builtin_amdgcn_s_setprio(0);
    cur ^= 1;
  }
#undef STAGE_TILE

  if constexpr (__is_same(OUT, float)) {
    // direct fp32 stores (64B segments)
    float* Cb = (float*)C + (long)z * strC;
#pragma unroll
    for (int m = 0; m < 4; ++m)
#pragma unroll
      for (int n = 0; n < 4; ++n) {
        const int gc = col * 128 + wc * 64 + n * 16 + lr;
        const float bv = bias ? bias[gc] : 0.0f;
#pragma unroll
        for (int j = 0; j < 4; ++j) {
          const int gr = row * 128 + wr * 64 + m * 16 + lg + j;
          Cb[(long)gr * N + gc] = acc[m][n][j] * scale + bv;
        }
      }
  } else if constexpr (MODE == 1) {
    // fp8 output: p = exp2(fma(s, scale*log2e, mb*log2e)) — 1 FMA + v_exp_f32
    FENCE;
    __builtin_amdgcn_s_barrier();  // staging LDS now reused as C tile (u8)
    FENCE;
    u8* sm8 = (u8*)smem;
    const float sL = scale * L2E;
    float mb[4];
#pragma unroll
    for (int n = 0; n < 4; ++n) {
      const int gc = col * 128 + wc * 64 + n * 16 + lr;
      mb[n] = (1.0f - mask[(long)z * SEQ + gc]) * (-10000.0f * L2E);
    }
    float rsv[4][4];
#pragma unroll
    for (int m = 0; m < 4; ++m)
#pragma unroll
      for (int j = 0; j < 4; ++j) rsv[m][j] = 0.0f;
#pragma unroll
    for (int m = 0; m < 4; ++m)
#pragma unroll
      for (int n = 0; n < 4; ++n) {
#pragma unroll
        for (int j = 0; j < 4; ++j) {
          const float v = EXP2(fmaf(acc[m][n][j], sL, mb[n]));
          rsv[m][j] += v;
          sm8[(wr * 64 + m * 16 + lg + j) * 128 + wc * 64 + n * 16 + lr] = to_fp8(v);
        }
      }
#pragma unroll
    for (int m = 0; m < 4; ++m)
#pragma unroll
      for (int j = 0; j < 4; ++j) {
        float v = rsv[m][j];
        v += __shfl_xor(v, 1); v += __shfl_xor(v, 2);
        v += __shfl_xor(v, 4); v += __shfl_xor(v, 8);
        if ((lane & 15) == 0) {
          const int gr = row * 128 + wr * 64 + m * 16 + lg + j;
          rspart[((long)z * NQ + gr) * 128 + col * 2 + wc] = v;
        }
      }
    __syncthreads();
    u8* Cb = (u8*)C + (long)z * strC;
    const long rb = (long)row * 128, cb = (long)col * 128;
#pragma unroll
    for (int i = 0; i < 4; ++i) {
      const int ch = tid + i * 256;  // 1024 chunks of 16B = 128x128 u8
      const int rr = ch >> 3;        // 8 chunks per 128-byte row
      const int ce = (ch & 7) * 16;
      *reinterpret_cast<u32x4*>(&Cb[(rb + rr) * (long)N + cb + ce]) =
          *reinterpret_cast<const u32x4*>(sm8 + ch * 16);
    }
  } else {
    // bf16 output with bias, LDS-bounced stores
    FENCE;
    __builtin_amdgcn_s_barrier();
    FENCE;
#pragma unroll
    for (int m = 0; m < 4; ++m)
#pragma unroll
      for (int n = 0; n < 4; ++n) {
        const int gc = col * 128 + wc * 64 + n * 16 + lr;
        const float bv = bias ? bias[gc] : 0.0f;
#pragma unroll
        for (int j = 0; j < 4; ++j)
          smem[(wr * 64 + m * 16 + lg + j) * 128 + wc * 64 + n * 16 + lr] =
              (bf16)(acc[m][n][j] * scale + bv);
      }
    __syncthreads();
    OUT* Cb = C + (long)z * strC;
    const long rb = (long)row * 128, cb = (long)col * 128;
#pragma unroll
    for (int i = 0; i < 8; ++i) {
      const int ch = tid + i * 256;
      const int rr = ch >> 4;
      const int ce = (ch & 15) * 8;
      *reinterpret_cast<bf16x8*>(&Cb[(rb + rr) * N + cb + ce]) =
          *reinterpret_cast<const bf16x8*>(smem + ch * 8);
    }
  }
}

// rowsum[row] = sum of 128 partial slots (deterministic reduce)
__global__ __launch_bounds__(256) void k_rowsum(const float* __restrict__ rp,
                                                float* __restrict__ rs) {
  const int t = threadIdx.x;
  const int row = blockIdx.x * 8 + (t >> 5);
  const int s = t & 31;
  const float* base = rp + (long)row * 128;
  float v = base[s] + base[s + 32] + base[s + 64] + base[s + 96];
  v += __shfl_xor(v, 1); v += __shfl_xor(v, 2); v += __shfl_xor(v, 4);
  v += __shfl_xor(v, 8); v += __shfl_xor(v, 16);
  if (s == 0) rs[row] = v;
}

// ---------------------------------------------------------------------------
// PHS split-K partial GEMM (FP8): Cpart[kc][b,q,:] = P8[b,q-tile,kc] . hsT8^T
// 128x128 tile, BK=32, mfma_f32_16x16x32_fp8_fp8; counted vmcnt(2).
__global__ __launch_bounds__(256) void k_gemm_phs(const u8* __restrict__ P,
                                                  const u8* __restrict__ HT,
                                                  bf16* __restrict__ Cp) {
  const int id = xcd_swz();
  const int col = id % 6;
  int r = id / 6;
  const int row = r % 8;
  r /= 8;
  const int b = r % 4;
  const int kc = r / 4;

  __shared__ char smem[32768];  // staging: A 2x4K @0, B 2x4K @8192; epilogue: bf16 tile
  u8* sm8 = (u8*)smem;

  const int tid = threadIdx.x;
  const int lane = tid & 63, wave = tid >> 6;
  const int wr = wave >> 1, wc = wave & 1;
  const int lr = lane & 15, l16 = lane >> 4;
  const int lg = l16 * 4;

  const u8* At = P + (long)b * NQ * SEQ + (long)row * 128 * SEQ + (long)kc * PHS_KC;
  const u8* Bt = HT + ((long)b * HIDDEN + (long)col * 128) * SEQ + (long)kc * PHS_KC;

#define STAGE_P8(buf, k0)                                                     \
  {                                                                           \
    u8* dA = sm8 + (buf) * 4096;                                              \
    u8* dB = sm8 + 8192 + (buf) * 4096;                                       \
    const int rr = tid >> 1, cc = (tid & 1) * 16;                             \
    GLOAD16(At + (long)rr * SEQ + (k0) + cc, dA + tid * 16);                  \
    GLOAD16(Bt + (long)rr * SEQ + (k0) + cc, dB + tid * 16);                  \
  }

  const int nt = PHS_KC / 32;  // 64
  STAGE_P8(0, 0);

  f32x4 acc[4][4] = {};
#pragma unroll 1
  for (int t = 0; t < nt; ++t) {
    FENCE;
    __builtin_amdgcn_s_barrier();
    FENCE;
    if (t + 1 < nt) {
      STAGE_P8((t + 1) & 1, (t + 1) * 32);
      asm volatile("s_waitcnt vmcnt(2)" ::: "memory");
    } else {
      asm volatile("s_waitcnt vmcnt(0)" ::: "memory");
    }
    __builtin_amdgcn_s_barrier();
    FENCE;
    const u8* rA = sm8 + (t & 1) * 4096;
    const u8* rB = sm8 + 8192 + (t & 1) * 4096;
    long af[4], bfr[4];
#pragma unroll
    for (int m = 0; m < 4; ++m)
      af[m] = *reinterpret_cast<const long*>(rA + (wr * 64 + m * 16 + lr) * 32 + l16 * 8);
#pragma unroll
    for (int n = 0; n < 4; ++n)
      bfr[n] = *reinterpret_cast<const long*>(rB + (wc * 64 + n * 16 + lr) * 32 + l16 * 8);
    __builtin_amdgcn_s_setprio(1);
#pragma unroll
    for (int m = 0; m < 4; ++m)
#pragma unroll
      for (int n = 0; n < 4; ++n)
        acc[m][n] = __builtin_amdgcn_mfma_f32_16x16x32_fp8_fp8(af[m], bfr[n], acc[m][n], 0, 0, 0);
    __builtin_amdgcn_s_setprio(0);
  }
#undef STAGE_P8

  FENCE;
  __builtin_amdgcn_s_barrier();
  FENCE;
  bf16* smb = (bf16*)smem;
#pragma unroll
  for (int m = 0; m < 4; ++m)
#pragma unroll
    for (int n = 0; n < 4; ++n)
#pragma unroll
      for (int j = 0; j < 4; ++j)
        smb[(wr * 64 + m * 16 + lg + j) * 128 + wc * 64 + n * 16 + lr] =
            (bf16)acc[m][n][j];
  __syncthreads();
  bf16* Co = Cp + ((long)kc * BATCH + b) * NQ * HIDDEN;
  const long rb = (long)row * 128, cb = (long)col * 128;
#pragma unroll
  for (int i = 0; i < 8; ++i) {
    const int ch = tid + i * 256;
    const int rr = ch >> 4;
    const int ce = (ch & 15) * 8;
    *reinterpret_cast<bf16x8*>(&Co[(rb + rr) * HIDDEN + cb + ce]) =
        *reinterpret_cast<const bf16x8*>(smb + ch * 8);
  }
}

// ---------------------------------------------------------------------------
// V-fold with inline partial-reduce + normalize:
// out[q,:] = ((sum_kc Ppart[kc][q,:]) / rowsum[q]) . Wv + bv
// A-operand register-staged (sum 4 partials, scale, ds_write); B via gload_lds.
// Safe __syncthreads dbuf loop (no manual vmcnt with mixed load types).
__global__ __launch_bounds__(256) void k_vfold(const bf16* __restrict__ Pp,
                                               const float* __restrict__ rs,
                                               const bf16* __restrict__ WvT,
                                               const float* __restrict__ bias,
                                               float* __restrict__ out) {
  const int id = xcd_swz();
  const int col = id % 6;   // 6 col-panels (768)
  const int row = id / 6;   // 32 row-panels (4096 q-rows)

  __shared__ bf16 smem[16384];

  const int tid = threadIdx.x;
  const int lane = tid & 63, wave = tid >> 6;
  const int wr = wave >> 1, wc = wave & 1;
  const int lr = lane & 15, lk = (lane >> 4) * 8, lg = (lane >> 4) * 4;

  const long NB = (long)BATCH * NQ * HIDDEN;
  const bf16* At = Pp + (long)row * 128 * HIDDEN;
  const bf16* Bt = WvT + (long)col * 128 * HIDDEN;
  const float inv0 = 1.0f / rs[row * 128 + (tid >> 2)];
  const float inv1 = 1.0f / rs[row * 128 + 64 + (tid >> 2)];

  auto STAGE = [&](int buf, int k0) {
    bf16* dA = smem + buf * 4096;
    bf16* dB = smem + 8192 + buf * 4096;
#pragma unroll
    for (int h = 0; h < 2; ++h) {
      const int c = tid + h * 256;
      const int rr = c >> 2, cc = (c & 3) * 8;
      float s8[8] = {};
#pragma unroll
      for (int kc = 0; kc < PHS_KS; ++kc) {
        bf16x8 v = *reinterpret_cast<const bf16x8*>(
            At + (long)kc * NB + (long)rr * HIDDEN + k0 + cc);
#pragma unroll
        for (int j = 0; j < 8; ++j) s8[j] += (float)v[j];
      }
      const float inv = h ? inv1 : inv0;
      bf16x8 o;
#pragma unroll
      for (int j = 0; j < 8; ++j) o[j] = (bf16)(s8[j] * inv);
      *reinterpret_cast<bf16x8*>(dA + c * 8) = o;
      GLOAD16(Bt + (long)rr * HIDDEN + k0 + cc, (char*)dB + c * 16);
    }
  };

  const int nt = HIDDEN / 32;  // 24
  STAGE(0, 0);
  __syncthreads();

  f32x4 acc[4][4] = {};
  int cur = 0;
#pragma unroll 1
  for (int t = 0; t < nt; ++t) {
    if (t + 1 < nt) STAGE(cur ^ 1, (t + 1) * 32);
    const bf16* rA = smem + cur * 4096;
    const bf16* rB = smem + 8192 + cur * 4096;
    bf16x8 af[4], bfr[4];
#pragma unroll
    for (int m = 0; m < 4; ++m)
      af[m] = *reinterpret_cast<const bf16x8*>(&rA[(wr * 64 + m * 16 + lr) * 32 + lk]);
#pragma unroll
    for (int n = 0; n < 4; ++n)
      bfr[n] = *reinterpret_cast<const bf16x8*>(&rB[(wc * 64 + n * 16 + lr) * 32 + lk]);
#pragma unroll
    for (int m = 0; m < 4; ++m)
#pragma unroll
      for (int n = 0; n < 4; ++n)
        acc[m][n] = __builtin_amdgcn_mfma_f32_16x16x32_bf16(af[m], bfr[n], acc[m][n], 0, 0, 0);
    __syncthreads();
    cur ^= 1;
  }

  // fp32 epilogue with bias (direct 64B-segment stores)
#pragma unroll
  for (int m = 0; m < 4; ++m)
#pragma unroll
    for (int n = 0; n < 4; ++n) {
      const int gc = col * 128 + wc * 64 + n * 16 + lr;
      const float bv = bias[gc];
#pragma unroll
      for (int j = 0; j < 4; ++j) {
        const int gr = row * 128 + wr * 64 + m * 16 + lg + j;
        out[(long)gr * HIDDEN + gc] = acc[m][n][j] + bv;
      }
    }
}

// ---------------------------------------------------------------------------
extern "C" void kernel_launch(void* const* d_in, const int* in_sizes, int n_in,
                              void* d_out, int out_size, void* d_ws, size_t ws_size,
                              hipStream_t stream) {
  const float* hs = (const float*)d_in[0];    // [B,S,H]
  const float* qu = (const float*)d_in[1];    // [B,Q,H]
  const float* mask = (const float*)d_in[2];  // [B,S]
  const float* Wq = (const float*)d_in[3];
  const float* bq = (const float*)d_in[4];
  const float* Wk = (const float*)d_in[5];
  const float* Wv = (const float*)d_in[7];
  const float* bv = (const float*)d_in[8];
  float* out = (float*)d_out;  // [B,Q,H] fp32
  // bk (d_in[6]) adds a softmax-row-constant -> cancels exactly.

  const size_t HS_N = (size_t)BATCH * SEQ * HIDDEN;
  const size_t QU_N = (size_t)BATCH * NQ * HIDDEN;
  const size_t W_N = (size_t)HIDDEN * HIDDEN;
  const size_t P_N = (size_t)BATCH * NQ * SEQ;

  char* ws = (char*)d_ws;
  size_t off = 0;
  auto alloc = [&](size_t bytes) {
    char* p = ws + off;
    off += (bytes + 255) & ~(size_t)255;
    return p;
  };

  // regionA: hsb (live through scores) / PHS partials (after) — overlap
  char* regionA = alloc(HS_N * 2);
  bf16* hsb = (bf16*)regionA;
  bf16* Ppart = (bf16*)regionA;        // PHS_KS(4) * QU_N bf16 = 25.2 MB
  u8* hsT8 = (u8*)alloc(HS_N);         // [B][H][S] fp8 e4m3
  u8* Pr = (u8*)alloc(P_N);            // unnormalized probs exp(s+mb), fp8
  bf16* qub = (bf16*)alloc(QU_N * 2);
  bf16* tmpb = (bf16*)alloc(QU_N * 2); // folded query: qu.(Wq.Wk^T) + bq.Wk^T
  bf16* Wkb = (bf16*)alloc(W_N * 2);
  bf16* Wqb = (bf16*)alloc(W_N * 2);
  bf16* WvT = (bf16*)alloc(W_N * 2);
  bf16* Mt = (bf16*)alloc(W_N * 2);    // Wk.Wq^T
  float* bqk = (float*)alloc(HIDDEN * 4);
  float* rspart = (float*)alloc((size_t)BATCH * NQ * 128 * 4);  // 2 MB
  float* rowsum = (float*)alloc((size_t)BATCH * NQ * 4);

  // 1) fused prep (qu cvt, Wk/Wq cvt, Wv transpose, bqk gemv) + hs prep
  k_prep<<<dim3(576, 4), dim3(256), 0, stream>>>(qu, qub, Wk, Wkb, Wq, Wqb,
                                                 Wv, WvT, bq, bqk);
  k_cvt_hs_dual<<<dim3(12, 1024), dim3(256), 0, stream>>>(hs, hsb, hsT8);

  // 2) Mt = Wk.Wq^T  [768x768]
  k_gemm_bt<bf16, 0><<<dim3(36), dim3(256), 0, stream>>>(
      Wkb, Wqb, Mt, nullptr, nullptr, nullptr, HIDDEN, HIDDEN, 1.0f, 6, 6, 0, 0, 0, 0);

  // 3) folded query: tmp = qub.Mt^T + bqk  [4096x768]
  k_gemm_bt<bf16, 0><<<dim3(192), dim3(256), 0, stream>>>(
      qub, Mt, tmpb, bqk, nullptr, nullptr, HIDDEN, HIDDEN, 1.0f, 6, 32, 0, 0, 0, 0);

  // 4) scores: Pr(fp8) = exp(tmp.hsb^T/sqrt(H) + maskbias), rowsum partials
  const float qkscale = 1.0f / sqrtf((float)HIDDEN);
  k_gemm_bt<u8, 1><<<dim3(2048), dim3(256), 0, stream>>>(
      tmpb, hsb, Pr, nullptr, mask, rspart, SEQ, HIDDEN, qkscale, 64, 8, 1,
      (long)NQ * HIDDEN, (long)SEQ * HIDDEN, (long)NQ * SEQ);
  k_rowsum<<<dim3(BATCH * NQ / 8), dim3(256), 0, stream>>>(rspart, rowsum);

  // 5) PHS partials (fp8 MFMA): Ppart[kc] = P8[:, kc-chunk] . hsT8^T
  k_gemm_phs<<<dim3(6 * 8 * 4 * PHS_KS), dim3(256), 0, stream>>>(Pr, hsT8, Ppart);

  // 6) V-fold with inline reduce+normalize: out = ((sum Ppart)/rowsum).Wv + bv
  k_vfold<<<dim3(192), dim3(256), 0, stream>>>(Ppart, rowsum, WvT, bv, out);
}